// Round 5
// baseline (323.943 us; speedup 1.0000x reference)
//
#include <hip/hip_runtime.h>
#include <math.h>

// Problem constants (from reference)
#define N        8192
#define C        128
#define E_TOTAL  262144
#define WPR      256          // bitmap words per row = N/32
#define INV_TEMP 2.0f         // 1/0.5
#define STEPS    10
#define S_ELL    96           // max dedup'd neighbors per row
#define ZROW     N            // zero row in bf16 buffers (row N kept zero)
#define POS_BLOCKS 2048
#define NEG_BLOCKS 128
#define BLOCKS   1024         // persistent grid: 4 blocks/CU on 256 CUs
#define NG       32           // groups for the bootstrap barrier
#define GSZ      (BLOCKS / NG)
#define NXCD     8

// ---- workspace layout (bytes) ----
#define OFF_BAR     0                             // 32 KB barrier state (host-memset)
#define BAR_BYTES   32768
#define OFF_BITMAP  BAR_BYTES                     // 8 MB (zeroed IN-KERNEL now)
#define BITMAP_BYTES (N * WPR * 4)
#define OFF_DINV    (OFF_BITMAP + BITMAP_BYTES)   // float dinvs[N]   32 KB
#define OFF_CNT     (OFF_DINV + 32768)            // int   cnt[N]     32 KB (fallback)
#define OFF_PART    (OFF_CNT + 32768)             // float part[2048] 8 KB
#define OFF_PNEG    (OFF_PART + 8192)             // float pneg[128]  1 KB (fallback)
#define OFF_ELL     (OFF_PNEG + 1024)             // int   ellc[N*96] 3 MB (fallback)
#define OFF_BUFA    (OFF_ELL + N * S_ELL * 4)     // bf16 (N+1)*C
#define OFF_BUFB    (OFF_BUFA + (N + 1) * C * 2)  // bf16 (N+1)*C

// ---- barrier state (uint index; one counter per 32-uint = 128 B line) ----
#define L_BGC(g)    ((g) * 32)           // bootstrap group counters   (0..31)
#define L_BRC       (32 * 32)            // bootstrap root counter
#define L_BF(g)     ((33 + (g)) * 32)    // bootstrap release flags    (33..64)
#define L_SARR(i)   ((65 + (i)) * 32)    // sub arrive counters        (65..96)
#define L_XARR(x)   ((97 + (x)) * 32)    // per-XCD arrive counters    (97..104)
#define L_XROOT     (105 * 32)           // root arrive counter
#define L_XFLAG(x)  ((106 + (x)) * 32)   // per-XCD release flags (root-set)
#define L_XFLAG2(x) ((114 + (x)) * 32)   // per-XCD "L2 inv done" (maint only)
#define L_SCNT(i)   ((122 + (i)) * 32)   // per-sub registration counts

// s_getreg imm for HW_REG_XCC_ID (id=20, offset=0, size=32): ((32-1)<<11)|20
#define XCC_ID_IMM 63508

typedef unsigned int        uint;
typedef unsigned short      ushort;
typedef unsigned long long  u64;

#define ALD(p)    __hip_atomic_load((p), __ATOMIC_RELAXED, __HIP_MEMORY_SCOPE_AGENT)
#define AST(p, v) __hip_atomic_store((p), (v), __ATOMIC_RELAXED, __HIP_MEMORY_SCOPE_AGENT)
#define AADD(p)   __hip_atomic_fetch_add((p), 1u, __ATOMIC_RELAXED, __HIP_MEMORY_SCOPE_AGENT)

__device__ __forceinline__ float bflo(uint u) { return __uint_as_float(u << 16); }
__device__ __forceinline__ float bfhi(uint u) { return __uint_as_float(u & 0xffff0000u); }
__device__ __forceinline__ ushort f2bf(float f) {   // RNE
    uint u = __float_as_uint(f);
    return (ushort)((u + 0x7fffu + ((u >> 16) & 1u)) >> 16);
}
__device__ __forceinline__ float dot_u(uint a, uint b) {
    return bflo(a) * bflo(b) + bfhi(a) * bfhi(b);
}
__device__ __forceinline__ float log_sigmoid(float z) {
    return fminf(z, 0.0f) - log1pf(expf(-fabsf(z)));
}
__device__ __forceinline__ void drain_vmem() {
    asm volatile("s_waitcnt vmcnt(0)" ::: "memory");
}

// ---------------------------------------------------------------------------
// Bootstrap counter barrier (phased, fence-free). All data crossing it is
// agent-scope (atomics / agent stores), already at LLC once each wave's
// vmcnt drains. No cache maintenance at all.
// ---------------------------------------------------------------------------
__device__ __forceinline__ void gsync_boot(uint* bar, uint phase, uint g) {
    drain_vmem();
    __syncthreads();
    if (threadIdx.x == 0) {
        uint old = AADD(&bar[L_BGC(g)]);
        if (old == phase * GSZ - 1u) {
            uint ro = AADD(&bar[L_BRC]);
            if (ro == phase * NG - 1u) {
                #pragma unroll
                for (uint i = 0; i < NG; ++i) AST(&bar[L_BF(i)], phase);
            }
        }
        while (ALD(&bar[L_BF(g)]) < phase) __builtin_amdgcn_s_sleep(1);
        __builtin_amdgcn_fence(__ATOMIC_ACQUIRE, "workgroup");  // order only
    }
    __syncthreads();
}

// ---------------------------------------------------------------------------
// FAST grid barrier: counter-only, ZERO cache maintenance, ONE flag hop.
// Valid because every datum crossing it moves via agent-scope (sc0 sc1)
// write-through stores / L2-bypass loads: writer drains vmcnt (stores at
// LLC) before arriving; reader's agent loads read LLC directly. 3-level
// arrive tree (32 sub -> 8 XCD -> root), monotone counters, no resets.
// ---------------------------------------------------------------------------
__device__ __forceinline__ void gsync_fast(uint* bar, uint phase, uint sid, uint xcd,
                                           uint scnt, uint sact, uint xact) {
    drain_vmem();
    __syncthreads();
    if (threadIdx.x == 0) {
        uint so = AADD(&bar[L_SARR(sid)]);
        if (so == phase * scnt - 1u) {
            uint xo = AADD(&bar[L_XARR(xcd)]);
            if (xo == phase * sact - 1u) {
                uint ro = AADD(&bar[L_XROOT]);
                if (ro == phase * xact - 1u) {
                    #pragma unroll
                    for (uint x = 0; x < NXCD; ++x) AST(&bar[L_XFLAG(x)], phase);
                }
            }
        }
        while (ALD(&bar[L_XFLAG(xcd)]) < phase) __builtin_amdgcn_s_sleep(1);
        __builtin_amdgcn_fence(__ATOMIC_ACQUIRE, "workgroup");  // order only
    }
    __syncthreads();
}

// ---------------------------------------------------------------------------
// MAINTENANCE barrier (used ONCE, before the loss phase): r4's proven
// leader-only acquire — per-XCD leader does the single agent-acquire fence
// (L1+L2 inv), non-leaders L1-inv only — so the loss phase can use plain
// cached loads on x. No wbl2 (x is already write-through at LLC).
// ---------------------------------------------------------------------------
__device__ __forceinline__ void gsync_maint(uint* bar, uint phase, uint sid, uint xcd,
                                            uint scnt, uint sact, uint xact) {
    drain_vmem();
    __syncthreads();
    if (threadIdx.x == 0) {
        bool leader = false;
        uint so = AADD(&bar[L_SARR(sid)]);
        if (so == phase * scnt - 1u) {
            uint xo = AADD(&bar[L_XARR(xcd)]);
            if (xo == phase * sact - 1u) {
                leader = true;
                uint ro = AADD(&bar[L_XROOT]);
                if (ro == phase * xact - 1u) {
                    #pragma unroll
                    for (uint x = 0; x < NXCD; ++x) AST(&bar[L_XFLAG(x)], phase);
                }
            }
        }
        if (leader) {
            while (ALD(&bar[L_XFLAG(xcd)]) < phase) __builtin_amdgcn_s_sleep(1);
            __builtin_amdgcn_fence(__ATOMIC_ACQUIRE, "agent");   // ONE L2 inv / XCD
            AST(&bar[L_XFLAG2(xcd)], phase);
        } else {
            while (ALD(&bar[L_XFLAG2(xcd)]) < phase) __builtin_amdgcn_s_sleep(1);
            asm volatile("buffer_inv sc0\n\t"
                         "s_waitcnt vmcnt(0)" ::: "memory");     // own-CU L1 only
        }
        __builtin_amdgcn_fence(__ATOMIC_ACQUIRE, "workgroup");
    }
    __syncthreads();
}

// ============================================================================
// Persistent mega-kernel. 1024 blocks x 256 threads; block owns 8 rows,
// wave owns 2; ELL lists live in LDS throughout. Cross-step data is
// agent-scope (write-through/L2-bypass) -> barriers are counter-only.
// ============================================================================
__global__ __launch_bounds__(256, 4) void mega_kernel(
        const float* __restrict__ emb,
        const int*   __restrict__ ei,
        const int*   __restrict__ ridx,
        float*       __restrict__ dinvs,
        float*       __restrict__ part,
        unsigned int* __restrict__ bm,
        uint*        __restrict__ bar,
        ushort*      __restrict__ bufA,
        ushort*      __restrict__ bufB,
        float*       __restrict__ out)
{
    __shared__ int   scol[8 * S_ELL];
    __shared__ int   sn[8];
    __shared__ float sds[8];
    __shared__ float red[256];

    const int  tid  = threadIdx.x;
    const int  bid  = blockIdx.x;
    const int  wid  = tid >> 6;
    const int  lane = tid & 63;
    const int  qw   = lane >> 4;
    const int  l16  = lane & 15;
    const int  gtid = bid * 256 + tid;
    const uint xcd  = __builtin_amdgcn_s_getreg(XCC_ID_IMM) & 7u;
    const uint sid  = xcd * 4u + (uint)(bid & 3);
    const uint bg   = (uint)(bid & (NG - 1));

    // ---- register this block's (xcd, sub) bucket ----
    if (tid == 0) AADD(&bar[L_SCNT(sid)]);

    // ---- phase 0: zero bitmap in-kernel (agent stores -> LLC, no L2 dirt);
    //      replaces the 8 MB hipMemsetAsync (~60-70 us in-graph, r1-vs-r2 gap)
    {
        u64* q = (u64*)bm;                       // 1 Mi qwords total
        #pragma unroll
        for (int i = 0; i < 4; ++i)
            AST(&q[gtid + i * (BLOCKS * 256)], 0ull);
        if (bid == 0 && tid < 64) {              // ZROW rows of both buffers
            AST(&((uint*)(bufA + (size_t)ZROW * C))[tid], 0u);
            AST(&((uint*)(bufB + (size_t)ZROW * C))[tid], 0u);
        }
    }
    gsync_boot(bar, 1, bg);

    // ---- phase 1: scatter edges (one edge/thread, agent atomics) ----
    {
        int s = ei[gtid];
        int t = ei[E_TOTAL + gtid];
        atomicOr(&bm[s * WPR + (t >> 5)], 1u << (t & 31));
    }
    gsync_boot(bar, 2, bg);

    // ---- bucket counts frozen: derive thresholds (tid0 only) ----
    uint scnt = 1, sact = 1, xact = 1;
    if (tid == 0) {
        xact = 0;
        #pragma unroll
        for (uint x = 0; x < NXCD; ++x) {
            uint nz = 0;
            #pragma unroll
            for (uint s2 = 0; s2 < 4; ++s2) {
                uint c = ALD(&bar[L_SCNT(x * 4u + s2)]);
                nz += (c != 0u);
                if (x * 4u + s2 == sid) scnt = (c ? c : 1u);
            }
            if (x == xcd) sact = (nz ? nz : 1u);
            xact += (nz != 0u);
        }
        if (xact == 0u) xact = 1u;
    }
    uint ph = 1;

    // ---- build ELL into LDS (agent bm loads: bypass any stale L2 lines) ----
    for (int rr = 0; rr < 2; ++rr) {
        int lr  = wid * 2 + rr;
        int row = bid * 8 + lr;
        unsigned int* p = bm + row * WPR;
        unsigned int w[4];
        int c = 0;
        #pragma unroll
        for (int i = 0; i < 4; ++i) { w[i] = ALD(&p[lane * 4 + i]); c += __popc(w[i]); }
        int inc = c;
        for (int off = 1; off < 64; off <<= 1) {
            int v = __shfl_up(inc, off, 64);
            if (lane >= off) inc += v;
        }
        int pos = inc - c;
        int total = __shfl(inc, 63, 64);
        for (int i = 0; i < 4; ++i) {
            unsigned int word = w[i];
            int jbase = (lane * 4 + i) << 5;
            while (word) {
                int b = __ffs(word) - 1;
                word &= word - 1;
                if (pos < S_ELL) scol[lr * S_ELL + pos] = jbase + b;
                ++pos;
            }
        }
        int ncap = (total < S_ELL) ? total : S_ELL;
        int npad = (ncap + 7) & ~7;                 // <= 96
        if (lane < npad - ncap)
            scol[lr * S_ELL + ncap + lane] = ZROW;
        if (lane == 0) {
            sn[lr]  = ncap;
            float ds = rsqrtf((float)total);        // deg >= 1 (self-loops)
            sds[lr] = ds;
            AST(&dinvs[row], ds);                   // write-through -> LLC
        }
    }
    gsync_fast(bar, ph++, sid, xcd, scnt, sact, xact);

    // ---- diffusion step 0 (emb read-only: plain cached; dinvs: agent) ----
    for (int rr = 0; rr < 2; ++rr) {
        int lr  = wid * 2 + rr;
        int row = bid * 8 + lr;
        int n   = sn[lr];
        const int* cr = scol + lr * S_ELL;
        float a0=0.f,a1=0.f,a2=0.f,a3=0.f,a4=0.f,a5=0.f,a6=0.f,a7=0.f;
        for (int k = 0; k < n; k += 8) {
            int i0 = k + qw, i1 = k + 4 + qw;
            int   c0 = (i0 < n) ? cr[i0] : row;
            int   c1 = (i1 < n) ? cr[i1] : row;
            float w0 = (i0 < n) ? ALD(&dinvs[c0]) : 0.0f;
            float w1 = (i1 < n) ? ALD(&dinvs[c1]) : 0.0f;
            const float* r0 = emb + c0 * C + l16 * 8;
            const float* r1 = emb + c1 * C + l16 * 8;
            float4 ua = *(const float4*)r0, ub = *(const float4*)(r0 + 4);
            float4 va = *(const float4*)r1, vb = *(const float4*)(r1 + 4);
            a0 += w0 * ua.x + w1 * va.x;  a1 += w0 * ua.y + w1 * va.y;
            a2 += w0 * ua.z + w1 * va.z;  a3 += w0 * ua.w + w1 * va.w;
            a4 += w0 * ub.x + w1 * vb.x;  a5 += w0 * ub.y + w1 * vb.y;
            a6 += w0 * ub.z + w1 * vb.z;  a7 += w0 * ub.w + w1 * vb.w;
        }
        a0 += __shfl_xor(a0, 16, 64); a0 += __shfl_xor(a0, 32, 64);
        a1 += __shfl_xor(a1, 16, 64); a1 += __shfl_xor(a1, 32, 64);
        a2 += __shfl_xor(a2, 16, 64); a2 += __shfl_xor(a2, 32, 64);
        a3 += __shfl_xor(a3, 16, 64); a3 += __shfl_xor(a3, 32, 64);
        a4 += __shfl_xor(a4, 16, 64); a4 += __shfl_xor(a4, 32, 64);
        a5 += __shfl_xor(a5, 16, 64); a5 += __shfl_xor(a5, 32, 64);
        a6 += __shfl_xor(a6, 16, 64); a6 += __shfl_xor(a6, 32, 64);
        a7 += __shfl_xor(a7, 16, 64); a7 += __shfl_xor(a7, 32, 64);
        if (qw == 0) {
            float ds = sds[lr];
            float sc = ds * ds;
            uint* po = (uint*)(bufB + row * C + l16 * 8);
            AST(&po[0], (uint)f2bf(a0 * sc) | ((uint)f2bf(a1 * sc) << 16));
            AST(&po[1], (uint)f2bf(a2 * sc) | ((uint)f2bf(a3 * sc) << 16));
            AST(&po[2], (uint)f2bf(a4 * sc) | ((uint)f2bf(a5 * sc) << 16));
            AST(&po[3], (uint)f2bf(a6 * sc) | ((uint)f2bf(a7 * sc) << 16));
        }
    }
    gsync_fast(bar, ph++, sid, xcd, scnt, sact, xact);

    // ---- steps 1..9 (bf16 ping-pong; agent loads = LLC-coherent) ----
    ushort* xb = bufB;
    ushort* yb = bufA;
    for (int s = 1; s < STEPS; ++s) {
        for (int rr = 0; rr < 2; ++rr) {
            int lr  = wid * 2 + rr;
            int row = bid * 8 + lr;
            int n   = sn[lr];
            int npad = (n + 7) & ~7;
            const int* cr = scol + lr * S_ELL;
            float a0=0.f,a1=0.f,a2=0.f,a3=0.f,a4=0.f,a5=0.f,a6=0.f,a7=0.f;
            for (int k = 0; k < npad; k += 8) {
                int c0 = cr[k + qw];
                int c1 = cr[k + 4 + qw];
                uint* p0 = (uint*)(xb + c0 * C + l16 * 8);
                uint* p1 = (uint*)(xb + c1 * C + l16 * 8);
                uint u0x = ALD(&p0[0]), u0y = ALD(&p0[1]), u0z = ALD(&p0[2]), u0w = ALD(&p0[3]);
                uint u1x = ALD(&p1[0]), u1y = ALD(&p1[1]), u1z = ALD(&p1[2]), u1w = ALD(&p1[3]);
                a0 += bflo(u0x) + bflo(u1x);  a1 += bfhi(u0x) + bfhi(u1x);
                a2 += bflo(u0y) + bflo(u1y);  a3 += bfhi(u0y) + bfhi(u1y);
                a4 += bflo(u0z) + bflo(u1z);  a5 += bfhi(u0z) + bfhi(u1z);
                a6 += bflo(u0w) + bflo(u1w);  a7 += bfhi(u0w) + bfhi(u1w);
            }
            a0 += __shfl_xor(a0, 16, 64); a0 += __shfl_xor(a0, 32, 64);
            a1 += __shfl_xor(a1, 16, 64); a1 += __shfl_xor(a1, 32, 64);
            a2 += __shfl_xor(a2, 16, 64); a2 += __shfl_xor(a2, 32, 64);
            a3 += __shfl_xor(a3, 16, 64); a3 += __shfl_xor(a3, 32, 64);
            a4 += __shfl_xor(a4, 16, 64); a4 += __shfl_xor(a4, 32, 64);
            a5 += __shfl_xor(a5, 16, 64); a5 += __shfl_xor(a5, 32, 64);
            a6 += __shfl_xor(a6, 16, 64); a6 += __shfl_xor(a6, 32, 64);
            a7 += __shfl_xor(a7, 16, 64); a7 += __shfl_xor(a7, 32, 64);
            if (qw == 0) {
                float ds = sds[lr];
                float sc = (s == STEPS - 1) ? ds : ds * ds;
                uint* po = (uint*)(yb + row * C + l16 * 8);
                AST(&po[0], (uint)f2bf(a0 * sc) | ((uint)f2bf(a1 * sc) << 16));
                AST(&po[1], (uint)f2bf(a2 * sc) | ((uint)f2bf(a3 * sc) << 16));
                AST(&po[2], (uint)f2bf(a4 * sc) | ((uint)f2bf(a5 * sc) << 16));
                AST(&po[3], (uint)f2bf(a6 * sc) | ((uint)f2bf(a7 * sc) << 16));
            }
        }
        if (s < STEPS - 1) gsync_fast (bar, ph++, sid, xcd, scnt, sact, xact);
        else               gsync_maint(bar, ph++, sid, xcd, scnt, sact, xact);
        ushort* t = xb; xb = yb; yb = t;
    }

    // ---- loss partials (plain cached loads; safe after maint barrier) ----
    {
        const ushort* x = xb;                        // final embeddings
        float sumP = 0.0f, sumN = 0.0f;
        int g    = lane >> 2;
        int q    = lane & 3;
        int wave = bid * 4 + wid;
        for (int base = wave * 16; base < E_TOTAL; base += BLOCKS * 4 * 16) {
            int e = base + g;
            int sI = ei[e];
            int tI = ei[E_TOTAL + e];
            const uint4* ps = (const uint4*)(x + sI * C + q * 32);
            const uint4* pt = (const uint4*)(x + tI * C + q * 32);
            uint4 s0 = ps[0], s1 = ps[1], s2 = ps[2], s3 = ps[3];
            uint4 t0 = pt[0], t1 = pt[1], t2 = pt[2], t3 = pt[3];
            float p = dot_u(s0.x, t0.x) + dot_u(s0.y, t0.y) + dot_u(s0.z, t0.z) + dot_u(s0.w, t0.w)
                    + dot_u(s1.x, t1.x) + dot_u(s1.y, t1.y) + dot_u(s1.z, t1.z) + dot_u(s1.w, t1.w)
                    + dot_u(s2.x, t2.x) + dot_u(s2.y, t2.y) + dot_u(s2.z, t2.z) + dot_u(s2.w, t2.w)
                    + dot_u(s3.x, t3.x) + dot_u(s3.y, t3.y) + dot_u(s3.z, t3.z) + dot_u(s3.w, t3.w);
            p += __shfl_xor(p, 1, 64);
            p += __shfl_xor(p, 2, 64);
            if (q == 0) sumP += log_sigmoid(p * INV_TEMP);
        }
        for (int base = wave * 16; base < N; base += BLOCKS * 4 * 16) {
            int i = base + g;
            int tI = ridx[i];
            const uint4* ps = (const uint4*)(x + i * C + q * 32);
            const uint4* pt = (const uint4*)(x + tI * C + q * 32);
            uint4 s0 = ps[0], s1 = ps[1], s2 = ps[2], s3 = ps[3];
            uint4 t0 = pt[0], t1 = pt[1], t2 = pt[2], t3 = pt[3];
            float p = dot_u(s0.x, t0.x) + dot_u(s0.y, t0.y) + dot_u(s0.z, t0.z) + dot_u(s0.w, t0.w)
                    + dot_u(s1.x, t1.x) + dot_u(s1.y, t1.y) + dot_u(s1.z, t1.z) + dot_u(s1.w, t1.w)
                    + dot_u(s2.x, t2.x) + dot_u(s2.y, t2.y) + dot_u(s2.z, t2.z) + dot_u(s2.w, t2.w)
                    + dot_u(s3.x, t3.x) + dot_u(s3.y, t3.y) + dot_u(s3.z, t3.z) + dot_u(s3.w, t3.w);
            p += __shfl_xor(p, 1, 64);
            p += __shfl_xor(p, 2, 64);
            if (q == 0) sumN += log_sigmoid(-p * INV_TEMP);
        }
        float v = sumP * (-1.0f / (float)E_TOTAL) + sumN * (-1.0f / (float)N);
        v += __shfl_xor(v, 4, 64);
        v += __shfl_xor(v, 8, 64);
        v += __shfl_xor(v, 16, 64);
        v += __shfl_xor(v, 32, 64);
        if (lane == 0) red[wid] = v;
        __syncthreads();
        if (tid == 0)
            AST(&part[bid], (red[0] + red[1]) + (red[2] + red[3]));  // -> LLC
    }
    gsync_fast(bar, ph++, sid, xcd, scnt, sact, xact);

    // ---- block 0 reduces 1024 partials (agent loads: LLC-fresh) ----
    if (bid == 0) {
        float s = ALD(&part[tid]) + ALD(&part[tid + 256])
                + ALD(&part[tid + 512]) + ALD(&part[tid + 768]);
        red[tid] = s;
        __syncthreads();
        for (int off = 128; off > 0; off >>= 1) {
            if (tid < off) red[tid] += red[tid + off];
            __syncthreads();
        }
        if (tid == 0) out[0] = red[0];
    }
}

// ============================================================================
// Fallback: proven multi-kernel path (if cooperative launch is rejected).
// ============================================================================
__global__ void scatter_edges_kernel(const int* __restrict__ ei,
                                     unsigned int* __restrict__ bm,
                                     ushort* __restrict__ bufA,
                                     ushort* __restrict__ bufB) {
    int tid = threadIdx.x;
    if (blockIdx.x < 2 && tid < 16) {
        ushort* zr = (blockIdx.x == 0) ? bufA : bufB;
        uint4 z; z.x = 0; z.y = 0; z.z = 0; z.w = 0;
        ((uint4*)(zr + (size_t)ZROW * C))[tid] = z;
    }
    int e = blockIdx.x * blockDim.x + tid;
    if (e >= E_TOTAL) return;
    int s = ei[e];
    int t = ei[E_TOTAL + e];
    atomicOr(&bm[s * WPR + (t >> 5)], 1u << (t & 31));
}

__global__ void build_ell_kernel(const unsigned int* __restrict__ bm,
                                 int* __restrict__ cnt,
                                 int* __restrict__ ellc,
                                 float* __restrict__ dinvs) {
    int wid  = threadIdx.x >> 6;
    int lane = threadIdx.x & 63;
    int row  = blockIdx.x * 4 + wid;
    const unsigned int* p = bm + row * WPR;
    unsigned int w[4];
    int c = 0;
    for (int i = 0; i < 4; ++i) { w[i] = p[lane * 4 + i]; c += __popc(w[i]); }
    int inc = c;
    for (int off = 1; off < 64; off <<= 1) {
        int v = __shfl_up(inc, off, 64);
        if (lane >= off) inc += v;
    }
    int pos = inc - c;
    int total = __shfl(inc, 63, 64);
    for (int i = 0; i < 4; ++i) {
        unsigned int word = w[i];
        int jbase = (lane * 4 + i) << 5;
        while (word) {
            int b = __ffs(word) - 1;
            word &= word - 1;
            if (pos < S_ELL) ellc[row * S_ELL + pos] = jbase + b;
            ++pos;
        }
    }
    int ncap = (total < S_ELL) ? total : S_ELL;
    int npad = (ncap + 7) & ~7;
    if (lane < npad - ncap)
        ellc[row * S_ELL + ncap + lane] = ZROW;
    if (lane == 0) {
        cnt[row] = ncap;
        dinvs[row] = rsqrtf((float)total);
    }
}

__global__ __launch_bounds__(256) void spmm_step_kernel(
        const int* __restrict__ cnt, const int* __restrict__ ellc,
        const float* __restrict__ dinvs, const void* __restrict__ xin,
        ushort* __restrict__ y, int first, int last) {
    __shared__ int   scol[4 * S_ELL];
    __shared__ int   sn[4];
    __shared__ float ssc[4];
    const int tid  = threadIdx.x;
    const int wid  = tid >> 6;
    const int lane = tid & 63;
    const int qw   = lane >> 4;
    const int l16  = lane & 15;

    for (int i = tid; i < 4 * S_ELL; i += 256)
        scol[i] = ellc[blockIdx.x * 4 * S_ELL + i];
    if (tid < 4) {
        int row = blockIdx.x * 4 + tid;
        sn[tid] = cnt[row];
        float ds = dinvs[row];
        ssc[tid] = last ? ds : ds * ds;
    }
    __syncthreads();

    int row = blockIdx.x * 4 + wid;
    int n = sn[wid];
    const int* cr = scol + wid * S_ELL;
    float a0=0.f,a1=0.f,a2=0.f,a3=0.f,a4=0.f,a5=0.f,a6=0.f,a7=0.f;
    if (first) {
        const float* x = (const float*)xin;
        for (int k = 0; k < n; k += 8) {
            int i0 = k + qw, i1 = k + 4 + qw;
            int   c0 = (i0 < n) ? cr[i0] : row;
            int   c1 = (i1 < n) ? cr[i1] : row;
            float w0 = (i0 < n) ? dinvs[c0] : 0.0f;
            float w1 = (i1 < n) ? dinvs[c1] : 0.0f;
            const float* r0 = x + c0 * C + l16 * 8;
            const float* r1 = x + c1 * C + l16 * 8;
            float4 ua = *(const float4*)r0, ub = *(const float4*)(r0 + 4);
            float4 va = *(const float4*)r1, vb = *(const float4*)(r1 + 4);
            a0 += w0 * ua.x + w1 * va.x;  a1 += w0 * ua.y + w1 * va.y;
            a2 += w0 * ua.z + w1 * va.z;  a3 += w0 * ua.w + w1 * va.w;
            a4 += w0 * ub.x + w1 * vb.x;  a5 += w0 * ub.y + w1 * vb.y;
            a6 += w0 * ub.z + w1 * vb.z;  a7 += w0 * ub.w + w1 * vb.w;
        }
    } else {
        const ushort* x = (const ushort*)xin;
        int npad = (n + 7) & ~7;
        for (int k = 0; k < npad; k += 8) {
            int c0 = cr[k + qw];
            int c1 = cr[k + 4 + qw];
            uint4 u0 = *(const uint4*)(x + c0 * C + l16 * 8);
            uint4 u1 = *(const uint4*)(x + c1 * C + l16 * 8);
            a0 += bflo(u0.x) + bflo(u1.x);  a1 += bfhi(u0.x) + bfhi(u1.x);
            a2 += bflo(u0.y) + bflo(u1.y);  a3 += bfhi(u0.y) + bfhi(u1.y);
            a4 += bflo(u0.z) + bflo(u1.z);  a5 += bfhi(u0.z) + bfhi(u1.z);
            a6 += bflo(u0.w) + bflo(u1.w);  a7 += bfhi(u0.w) + bfhi(u1.w);
        }
    }
    a0 += __shfl_xor(a0, 16, 64); a0 += __shfl_xor(a0, 32, 64);
    a1 += __shfl_xor(a1, 16, 64); a1 += __shfl_xor(a1, 32, 64);
    a2 += __shfl_xor(a2, 16, 64); a2 += __shfl_xor(a2, 32, 64);
    a3 += __shfl_xor(a3, 16, 64); a3 += __shfl_xor(a3, 32, 64);
    a4 += __shfl_xor(a4, 16, 64); a4 += __shfl_xor(a4, 32, 64);
    a5 += __shfl_xor(a5, 16, 64); a5 += __shfl_xor(a5, 32, 64);
    a6 += __shfl_xor(a6, 16, 64); a6 += __shfl_xor(a6, 32, 64);
    a7 += __shfl_xor(a7, 16, 64); a7 += __shfl_xor(a7, 32, 64);
    if (qw == 0) {
        float sc = ssc[wid];
        uint4 o;
        o.x = (uint)f2bf(a0 * sc) | ((uint)f2bf(a1 * sc) << 16);
        o.y = (uint)f2bf(a2 * sc) | ((uint)f2bf(a3 * sc) << 16);
        o.z = (uint)f2bf(a4 * sc) | ((uint)f2bf(a5 * sc) << 16);
        o.w = (uint)f2bf(a6 * sc) | ((uint)f2bf(a7 * sc) << 16);
        *(uint4*)(y + row * C + l16 * 8) = o;
    }
}

__global__ void loss_kernel(const ushort* __restrict__ x,
                            const int* __restrict__ ei,
                            const int* __restrict__ ridx,
                            float* __restrict__ ppos,
                            float* __restrict__ pneg) {
    __shared__ float wsum[4];
    int lane = threadIdx.x & 63;
    int g    = lane >> 2;
    int q    = lane & 3;
    float sum = 0.0f;
    if (blockIdx.x < POS_BLOCKS) {
        int wave = (blockIdx.x * blockDim.x + threadIdx.x) >> 6;
        int nwaves = (POS_BLOCKS * 256) >> 6;
        for (int base = wave * 16; base < E_TOTAL; base += nwaves * 16) {
            int e = base + g;
            int s = ei[e];
            int t = ei[E_TOTAL + e];
            const uint4* ps = (const uint4*)(x + s * C + q * 32);
            const uint4* pt = (const uint4*)(x + t * C + q * 32);
            uint4 s0 = ps[0], s1 = ps[1], s2 = ps[2], s3 = ps[3];
            uint4 t0 = pt[0], t1 = pt[1], t2 = pt[2], t3 = pt[3];
            float p = dot_u(s0.x, t0.x) + dot_u(s0.y, t0.y) + dot_u(s0.z, t0.z) + dot_u(s0.w, t0.w)
                    + dot_u(s1.x, t1.x) + dot_u(s1.y, t1.y) + dot_u(s1.z, t1.z) + dot_u(s1.w, t1.w)
                    + dot_u(s2.x, t2.x) + dot_u(s2.y, t2.y) + dot_u(s2.z, t2.z) + dot_u(s2.w, t2.w)
                    + dot_u(s3.x, t3.x) + dot_u(s3.y, t3.y) + dot_u(s3.z, t3.z) + dot_u(s3.w, t3.w);
            p += __shfl_xor(p, 1, 64);
            p += __shfl_xor(p, 2, 64);
            if (q == 0) sum += log_sigmoid(p * INV_TEMP);
        }
    } else {
        int bi = blockIdx.x - POS_BLOCKS;
        int wave = (bi * blockDim.x + threadIdx.x) >> 6;
        int nwaves = (NEG_BLOCKS * 256) >> 6;
        for (int base = wave * 16; base < N; base += nwaves * 16) {
            int i = base + g;
            int t = ridx[i];
            const uint4* ps = (const uint4*)(x + i * C + q * 32);
            const uint4* pt = (const uint4*)(x + t * C + q * 32);
            uint4 s0 = ps[0], s1 = ps[1], s2 = ps[2], s3 = ps[3];
            uint4 t0 = pt[0], t1 = pt[1], t2 = pt[2], t3 = pt[3];
            float p = dot_u(s0.x, t0.x) + dot_u(s0.y, t0.y) + dot_u(s0.z, t0.z) + dot_u(s0.w, t0.w)
                    + dot_u(s1.x, t1.x) + dot_u(s1.y, t1.y) + dot_u(s1.z, t1.z) + dot_u(s1.w, t1.w)
                    + dot_u(s2.x, t2.x) + dot_u(s2.y, t2.y) + dot_u(s2.z, t2.z) + dot_u(s2.w, t2.w)
                    + dot_u(s3.x, t3.x) + dot_u(s3.y, t3.y) + dot_u(s3.z, t3.z) + dot_u(s3.w, t3.w);
            p += __shfl_xor(p, 1, 64);
            p += __shfl_xor(p, 2, 64);
            if (q == 0) sum += log_sigmoid(-p * INV_TEMP);
        }
    }
    sum += __shfl_xor(sum, 4, 64);
    sum += __shfl_xor(sum, 8, 64);
    sum += __shfl_xor(sum, 16, 64);
    sum += __shfl_xor(sum, 32, 64);
    if (lane == 0) wsum[threadIdx.x >> 6] = sum;
    __syncthreads();
    if (threadIdx.x == 0) {
        float v = (wsum[0] + wsum[1]) + (wsum[2] + wsum[3]);
        if (blockIdx.x < POS_BLOCKS) ppos[blockIdx.x] = v;
        else                         pneg[blockIdx.x - POS_BLOCKS] = v;
    }
}

__global__ void finalize_kernel(const float* __restrict__ ppos,
                                const float* __restrict__ pneg,
                                float* __restrict__ out) {
    __shared__ float red[256];
    int t = threadIdx.x;
    float s = 0.0f;
    for (int i = t; i < POS_BLOCKS; i += 256) s += ppos[i];
    float sn = (t < NEG_BLOCKS) ? pneg[t] : 0.0f;
    red[t] = s * (-1.0f / (float)E_TOTAL) + sn * (-1.0f / (float)N);
    __syncthreads();
    for (int off = 128; off > 0; off >>= 1) {
        if (t < off) red[t] += red[t + off];
        __syncthreads();
    }
    if (t == 0) out[0] = red[0];
}

extern "C" void kernel_launch(void* const* d_in, const int* in_sizes, int n_in,
                              void* d_out, int out_size, void* d_ws, size_t ws_size,
                              hipStream_t stream) {
    (void)in_sizes; (void)n_in; (void)out_size; (void)ws_size;

    const float* emb_in = (const float*)d_in[0];
    const int*   ei     = (const int*)d_in[1];   // (2, E) flattened: src then dst
    const int*   ridx   = (const int*)d_in[2];
    float* out = (float*)d_out;

    char* ws = (char*)d_ws;
    uint*         bar   = (uint*)(ws + OFF_BAR);
    unsigned int* bm    = (unsigned int*)(ws + OFF_BITMAP);
    float*        dinvs = (float*)(ws + OFF_DINV);
    int*          cnt   = (int*)(ws + OFF_CNT);
    float*        part  = (float*)(ws + OFF_PART);
    float*        pneg  = (float*)(ws + OFF_PNEG);
    int*          ellc  = (int*)(ws + OFF_ELL);
    ushort*       bufA  = (ushort*)(ws + OFF_BUFA);
    ushort*       bufB  = (ushort*)(ws + OFF_BUFB);

    // tiny memset: barrier state only (bitmap is zeroed in-kernel now)
    hipMemsetAsync(ws + OFF_BAR, 0, BAR_BYTES, stream);

    void* args[] = { (void*)&emb_in, (void*)&ei, (void*)&ridx, (void*)&dinvs,
                     (void*)&part,   (void*)&bm, (void*)&bar,  (void*)&bufA,
                     (void*)&bufB,   (void*)&out };
    hipError_t rc = hipLaunchCooperativeKernel(
        reinterpret_cast<void*>(mega_kernel),
        dim3(BLOCKS), dim3(256), args, 0, stream);

    if (rc != hipSuccess) {
        // Fallback: proven multi-kernel path (needs its own bitmap memset).
        ushort* buf[2] = {bufA, bufB};
        hipMemsetAsync(bm, 0, BITMAP_BYTES, stream);
        scatter_edges_kernel<<<E_TOTAL / 256, 256, 0, stream>>>(ei, bm, bufA, bufB);
        build_ell_kernel<<<N / 4, 256, 0, stream>>>(bm, cnt, ellc, dinvs);
        for (int s = 0; s < STEPS; ++s) {
            const void* xs = (s == 0) ? (const void*)emb_in : (const void*)buf[s & 1];
            ushort* yd = buf[(s + 1) & 1];
            spmm_step_kernel<<<N / 4, 256, 0, stream>>>(cnt, ellc, dinvs, xs, yd,
                                                        s == 0 ? 1 : 0,
                                                        s == STEPS - 1 ? 1 : 0);
        }
        const ushort* emb = buf[STEPS & 1];
        loss_kernel<<<POS_BLOCKS + NEG_BLOCKS, 256, 0, stream>>>(emb, ei, ridx, part, pneg);
        finalize_kernel<<<1, 256, 0, stream>>>(part, pneg, out);
    }
}

// Round 6
// 228.170 us; speedup vs baseline: 1.4197x; 1.4197x over previous
//
#include <hip/hip_runtime.h>
#include <math.h>

// Problem constants (from reference)
#define N        8192
#define C        128
#define E_TOTAL  262144
#define WPR      256          // bitmap words per row = N/32
#define INV_TEMP 2.0f         // 1/0.5
#define STEPS    10
#define S_ELL    96           // max dedup'd neighbors per row
#define ZROW     N            // zero row in bf16 buffers (row N kept zero)
#define POS_BLOCKS 2048
#define NEG_BLOCKS 128
#define BLOCKS   1024         // persistent grid: 4 blocks/CU on 256 CUs
#define NG       32           // groups for the bootstrap barrier
#define GSZ      (BLOCKS / NG)
#define NXCD     8

// ---- workspace layout (bytes) ----
// bar + bitmap contiguous so ONE hipMemsetAsync zeroes both (r4-proven).
#define OFF_BAR     0                             // 32 KB barrier state
#define BAR_BYTES   32768
#define OFF_BITMAP  BAR_BYTES                     // 8 MB
#define BITMAP_BYTES (N * WPR * 4)
#define OFF_DINV    (OFF_BITMAP + BITMAP_BYTES)   // float dinvs[N]   32 KB
#define OFF_CNT     (OFF_DINV + 32768)            // int   cnt[N]     32 KB (fallback)
#define OFF_PART    (OFF_CNT + 32768)             // float part[2048] 8 KB
#define OFF_PNEG    (OFF_PART + 8192)             // float pneg[128]  1 KB (fallback)
#define OFF_ELL     (OFF_PNEG + 1024)             // int   ellc[N*96] 3 MB (fallback)
#define OFF_BUFA    (OFF_ELL + N * S_ELL * 4)     // bf16 (N+1)*C
#define OFF_BUFB    (OFF_BUFA + (N + 1) * C * 2)  // bf16 (N+1)*C

// ---- barrier state (uint index; one counter per 32-uint = 128 B line) ----
#define L_BGC(g)    ((g) * 32)           // bootstrap group counters   (0..31)
#define L_BRC       (32 * 32)            // bootstrap root counter
#define L_BF(g)     ((33 + (g)) * 32)    // bootstrap release flags
#define L_SARR(i)   ((65 + (i)) * 32)    // sub arrive counters (32)
#define L_XARR(x)   ((97 + (x)) * 32)    // per-XCD arrive counters (8)
#define L_XROOT     (105 * 32)           // root arrive counter
#define L_XFLAG(x)  ((106 + (x)) * 32)   // per-XCD release flags (root-set)
#define L_XFLAG2(x) ((114 + (x)) * 32)   // per-XCD "L2 inv done" (maint only)
#define L_SCNT(i)   ((122 + (i)) * 32)   // per-sub registration counts
#define L_PDONE     (154 * 32)           // loss-partials-done counter

// s_getreg imm for HW_REG_XCC_ID (id=20, offset=0, size=32): ((32-1)<<11)|20
#define XCC_ID_IMM 63508

typedef unsigned int        uint;
typedef unsigned short      ushort;
typedef unsigned long long  u64;

#define ALD(p)     __hip_atomic_load((p), __ATOMIC_RELAXED, __HIP_MEMORY_SCOPE_AGENT)
#define AST(p, v)  __hip_atomic_store((p), (v), __ATOMIC_RELAXED, __HIP_MEMORY_SCOPE_AGENT)
#define AST64(p, v) __hip_atomic_store((p), (v), __ATOMIC_RELAXED, __HIP_MEMORY_SCOPE_AGENT)
#define AADD(p)    __hip_atomic_fetch_add((p), 1u, __ATOMIC_RELAXED, __HIP_MEMORY_SCOPE_AGENT)

__device__ __forceinline__ float bflo(uint u) { return __uint_as_float(u << 16); }
__device__ __forceinline__ float bfhi(uint u) { return __uint_as_float(u & 0xffff0000u); }
__device__ __forceinline__ ushort f2bf(float f) {   // RNE
    uint u = __float_as_uint(f);
    return (ushort)((u + 0x7fffu + ((u >> 16) & 1u)) >> 16);
}
__device__ __forceinline__ uint pk(float lo, float hi) {
    return (uint)f2bf(lo) | ((uint)f2bf(hi) << 16);
}
__device__ __forceinline__ float dot_u(uint a, uint b) {
    return bflo(a) * bflo(b) + bfhi(a) * bfhi(b);
}
__device__ __forceinline__ float log_sigmoid(float z) {
    return fminf(z, 0.0f) - log1pf(expf(-fabsf(z)));
}
__device__ __forceinline__ void drain_vmem() {
    asm volatile("s_waitcnt vmcnt(0)" ::: "memory");
}

// ---------------------------------------------------------------------------
// Bootstrap counter barrier (fence-free, used once after scatter). All data
// crossing it is agent-scope (atomicOr / SCNT RMWs), already at LLC after
// each wave's vmcnt drain; bm lines were never cached -> reads are fresh.
// ---------------------------------------------------------------------------
__device__ __forceinline__ void gsync_boot(uint* bar, uint g) {
    drain_vmem();
    __syncthreads();
    if (threadIdx.x == 0) {
        uint old = AADD(&bar[L_BGC(g)]);
        if (old == GSZ - 1u) {
            uint ro = AADD(&bar[L_BRC]);
            if (ro == NG - 1u) {
                #pragma unroll
                for (uint i = 0; i < NG; ++i) AST(&bar[L_BF(i)], 1u);
            }
        }
        while (ALD(&bar[L_BF(g)]) < 1u) __builtin_amdgcn_s_sleep(1);
        __builtin_amdgcn_fence(__ATOMIC_ACQUIRE, "workgroup");  // order only
    }
    __syncthreads();
}

// ---------------------------------------------------------------------------
// LITE barrier: counter-only, no cache maintenance. Safe only when every
// global line read after it either (a) moved via write-through agent stores
// AND (b) was never read (cached) before in this kernel. Used after build /
// step0 / step1 (first read of each ping-pong buffer).
// ---------------------------------------------------------------------------
__device__ __forceinline__ void gsync_lite(uint* bar, uint phase, uint sid, uint xcd,
                                           uint scnt, uint sact, uint xact) {
    drain_vmem();
    __syncthreads();
    if (threadIdx.x == 0) {
        uint so = AADD(&bar[L_SARR(sid)]);
        if (so == phase * scnt - 1u) {
            uint xo = AADD(&bar[L_XARR(xcd)]);
            if (xo == phase * sact - 1u) {
                uint ro = AADD(&bar[L_XROOT]);   // RELAXED: nothing dirty anywhere
                if (ro == phase * xact - 1u) {
                    #pragma unroll
                    for (uint x = 0; x < NXCD; ++x) AST(&bar[L_XFLAG(x)], phase);
                }
            }
        }
        while (ALD(&bar[L_XFLAG(xcd)]) < phase) __builtin_amdgcn_s_sleep(1);
        __builtin_amdgcn_fence(__ATOMIC_ACQUIRE, "workgroup");  // order only
    }
    __syncthreads();
}

// ---------------------------------------------------------------------------
// MAINT barrier: counter tree (all relaxed — stores are write-through so no
// wbl2 release is ever needed) + leader-only CLEAN L2 invalidate (nothing is
// dirty, so the inv is a tag-walk with zero writeback traffic), followers
// L1-inv only. Needed whenever the next phase re-reads lines that readers
// cached 2 steps ago (steps 2..9 and the pre-loss barrier).
// ---------------------------------------------------------------------------
__device__ __forceinline__ void gsync_maint(uint* bar, uint phase, uint sid, uint xcd,
                                            uint scnt, uint sact, uint xact) {
    drain_vmem();
    __syncthreads();
    if (threadIdx.x == 0) {
        bool leader = false;
        uint so = AADD(&bar[L_SARR(sid)]);
        if (so == phase * scnt - 1u) {
            uint xo = AADD(&bar[L_XARR(xcd)]);
            if (xo == phase * sact - 1u) {
                leader = true;
                uint ro = AADD(&bar[L_XROOT]);   // relaxed: no dirty data
                if (ro == phase * xact - 1u) {
                    #pragma unroll
                    for (uint x = 0; x < NXCD; ++x) AST(&bar[L_XFLAG(x)], phase);
                }
            }
        }
        if (leader) {
            while (ALD(&bar[L_XFLAG(xcd)]) < phase) __builtin_amdgcn_s_sleep(1);
            __builtin_amdgcn_fence(__ATOMIC_ACQUIRE, "agent");   // ONE clean L2 inv / XCD
            AST(&bar[L_XFLAG2(xcd)], phase);
        } else {
            while (ALD(&bar[L_XFLAG2(xcd)]) < phase) __builtin_amdgcn_s_sleep(1);
            asm volatile("buffer_inv sc0\n\t"
                         "s_waitcnt vmcnt(0)" ::: "memory");     // own-CU L1 only
        }
        __builtin_amdgcn_fence(__ATOMIC_ACQUIRE, "workgroup");
    }
    __syncthreads();
}

// ============================================================================
// Persistent mega-kernel. 1024 blocks x 256 threads; block owns 8 rows,
// wave owns 2; ELL lists live in LDS throughout. Gathers: plain cached b128
// (L2-resident x, r4-fast). Cross-step stores: write-through u64 agent
// stores -> L2 never dirty -> barriers need no wbl2.
// ============================================================================
__global__ __launch_bounds__(256, 4) void mega_kernel(
        const float* __restrict__ emb,
        const int*   __restrict__ ei,
        const int*   __restrict__ ridx,
        float*       __restrict__ dinvs,
        float*       __restrict__ part,
        unsigned int* __restrict__ bm,
        uint*        __restrict__ bar,
        ushort*      __restrict__ bufA,
        ushort*      __restrict__ bufB,
        float*       __restrict__ out)
{
    __shared__ int   scol[8 * S_ELL];
    __shared__ int   sn[8];
    __shared__ float sds[8];
    __shared__ float red[256];

    const int  tid  = threadIdx.x;
    const int  bid  = blockIdx.x;
    const int  wid  = tid >> 6;
    const int  lane = tid & 63;
    const int  qw   = lane >> 4;
    const int  l16  = lane & 15;
    const int  gtid = bid * 256 + tid;
    const uint xcd  = __builtin_amdgcn_s_getreg(XCC_ID_IMM) & 7u;
    const uint sid  = xcd * 4u + (uint)(bid & 3);
    const uint bg   = (uint)(bid & (NG - 1));

    // ---- register this block's (xcd, sub) bucket ----
    if (tid == 0) AADD(&bar[L_SCNT(sid)]);

    // ---- phase: scatter edges (agent atomics) + ZROW zero (write-through) ----
    {
        if (bid == 0 && tid < 32) {
            u64* za = (u64*)(bufA + (size_t)ZROW * C);
            u64* zb = (u64*)(bufB + (size_t)ZROW * C);
            if (tid < 16) AST64(&za[tid], 0ull);
            else          AST64(&zb[tid - 16], 0ull);
        }
        int s = ei[gtid];
        int t = ei[E_TOTAL + gtid];
        atomicOr(&bm[s * WPR + (t >> 5)], 1u << (t & 31));
    }
    gsync_boot(bar, bg);

    // ---- bucket counts frozen: derive thresholds (tid0 only) ----
    uint scnt = 1, sact = 1, xact = 1;
    if (tid == 0) {
        xact = 0;
        #pragma unroll
        for (uint x = 0; x < NXCD; ++x) {
            uint nz = 0;
            #pragma unroll
            for (uint s2 = 0; s2 < 4; ++s2) {
                uint c = ALD(&bar[L_SCNT(x * 4u + s2)]);
                nz += (c != 0u);
                if (x * 4u + s2 == sid) scnt = (c ? c : 1u);
            }
            if (x == xcd) sact = (nz ? nz : 1u);
            xact += (nz != 0u);
        }
        if (xact == 0u) xact = 1u;
    }
    uint ph = 1;

    // ---- build ELL into LDS (plain bm reads: first touch, fresh from LLC) ----
    for (int rr = 0; rr < 2; ++rr) {
        int lr  = wid * 2 + rr;
        int row = bid * 8 + lr;
        const unsigned int* p = bm + row * WPR;
        unsigned int w[4];
        int c = 0;
        #pragma unroll
        for (int i = 0; i < 4; ++i) { w[i] = p[lane * 4 + i]; c += __popc(w[i]); }
        int inc = c;
        for (int off = 1; off < 64; off <<= 1) {
            int v = __shfl_up(inc, off, 64);
            if (lane >= off) inc += v;
        }
        int pos = inc - c;
        int total = __shfl(inc, 63, 64);
        for (int i = 0; i < 4; ++i) {
            unsigned int word = w[i];
            int jbase = (lane * 4 + i) << 5;
            while (word) {
                int b = __ffs(word) - 1;
                word &= word - 1;
                if (pos < S_ELL) scol[lr * S_ELL + pos] = jbase + b;
                ++pos;
            }
        }
        int ncap = (total < S_ELL) ? total : S_ELL;
        int npad = (ncap + 7) & ~7;                 // <= 96
        if (lane < npad - ncap)
            scol[lr * S_ELL + ncap + lane] = ZROW;
        if (lane == 0) {
            sn[lr]  = ncap;
            float ds = rsqrtf((float)total);        // deg >= 1 (self-loops)
            sds[lr] = ds;
            AST(&dinvs[row], ds);                   // write-through -> LLC
        }
    }
    gsync_lite(bar, ph++, sid, xcd, scnt, sact, xact);  // dinvs: first-read next

    // ---- diffusion step 0 (plain cached gathers; r4-identical math) ----
    for (int rr = 0; rr < 2; ++rr) {
        int lr  = wid * 2 + rr;
        int row = bid * 8 + lr;
        int n   = sn[lr];
        const int* cr = scol + lr * S_ELL;
        float a0=0.f,a1=0.f,a2=0.f,a3=0.f,a4=0.f,a5=0.f,a6=0.f,a7=0.f;
        for (int k = 0; k < n; k += 8) {
            int i0 = k + qw, i1 = k + 4 + qw;
            int   c0 = (i0 < n) ? cr[i0] : row;
            int   c1 = (i1 < n) ? cr[i1] : row;
            float w0 = (i0 < n) ? dinvs[c0] : 0.0f;
            float w1 = (i1 < n) ? dinvs[c1] : 0.0f;
            const float* r0 = emb + c0 * C + l16 * 8;
            const float* r1 = emb + c1 * C + l16 * 8;
            float4 ua = *(const float4*)r0, ub = *(const float4*)(r0 + 4);
            float4 va = *(const float4*)r1, vb = *(const float4*)(r1 + 4);
            a0 += w0 * ua.x + w1 * va.x;  a1 += w0 * ua.y + w1 * va.y;
            a2 += w0 * ua.z + w1 * va.z;  a3 += w0 * ua.w + w1 * va.w;
            a4 += w0 * ub.x + w1 * vb.x;  a5 += w0 * ub.y + w1 * vb.y;
            a6 += w0 * ub.z + w1 * vb.z;  a7 += w0 * ub.w + w1 * vb.w;
        }
        a0 += __shfl_xor(a0, 16, 64); a0 += __shfl_xor(a0, 32, 64);
        a1 += __shfl_xor(a1, 16, 64); a1 += __shfl_xor(a1, 32, 64);
        a2 += __shfl_xor(a2, 16, 64); a2 += __shfl_xor(a2, 32, 64);
        a3 += __shfl_xor(a3, 16, 64); a3 += __shfl_xor(a3, 32, 64);
        a4 += __shfl_xor(a4, 16, 64); a4 += __shfl_xor(a4, 32, 64);
        a5 += __shfl_xor(a5, 16, 64); a5 += __shfl_xor(a5, 32, 64);
        a6 += __shfl_xor(a6, 16, 64); a6 += __shfl_xor(a6, 32, 64);
        a7 += __shfl_xor(a7, 16, 64); a7 += __shfl_xor(a7, 32, 64);
        if (qw == 0) {
            float ds = sds[lr];
            float sc = ds * ds;                     // step 0 is never last
            u64 lo = (u64)pk(a0 * sc, a1 * sc) | ((u64)pk(a2 * sc, a3 * sc) << 32);
            u64 hi = (u64)pk(a4 * sc, a5 * sc) | ((u64)pk(a6 * sc, a7 * sc) << 32);
            u64* po = (u64*)(bufB + row * C + l16 * 8);
            AST64(&po[0], lo);
            AST64(&po[1], hi);
        }
    }
    gsync_lite(bar, ph++, sid, xcd, scnt, sact, xact);  // bufB: first-read next

    // ---- steps 1..9 (bf16 ping-pong; cached b128 gathers) ----
    ushort* xb = bufB;
    ushort* yb = bufA;
    for (int s = 1; s < STEPS; ++s) {
        for (int rr = 0; rr < 2; ++rr) {
            int lr  = wid * 2 + rr;
            int row = bid * 8 + lr;
            int n   = sn[lr];
            int npad = (n + 7) & ~7;                // ZROW-padded; row ZROW zero
            const int* cr = scol + lr * S_ELL;
            float a0=0.f,a1=0.f,a2=0.f,a3=0.f,a4=0.f,a5=0.f,a6=0.f,a7=0.f;
            for (int k = 0; k < npad; k += 8) {
                int c0 = cr[k + qw];
                int c1 = cr[k + 4 + qw];
                uint4 u0 = *(const uint4*)(xb + c0 * C + l16 * 8);
                uint4 u1 = *(const uint4*)(xb + c1 * C + l16 * 8);
                a0 += bflo(u0.x) + bflo(u1.x);  a1 += bfhi(u0.x) + bfhi(u1.x);
                a2 += bflo(u0.y) + bflo(u1.y);  a3 += bfhi(u0.y) + bfhi(u1.y);
                a4 += bflo(u0.z) + bflo(u1.z);  a5 += bfhi(u0.z) + bfhi(u1.z);
                a6 += bflo(u0.w) + bflo(u1.w);  a7 += bfhi(u0.w) + bfhi(u1.w);
            }
            a0 += __shfl_xor(a0, 16, 64); a0 += __shfl_xor(a0, 32, 64);
            a1 += __shfl_xor(a1, 16, 64); a1 += __shfl_xor(a1, 32, 64);
            a2 += __shfl_xor(a2, 16, 64); a2 += __shfl_xor(a2, 32, 64);
            a3 += __shfl_xor(a3, 16, 64); a3 += __shfl_xor(a3, 32, 64);
            a4 += __shfl_xor(a4, 16, 64); a4 += __shfl_xor(a4, 32, 64);
            a5 += __shfl_xor(a5, 16, 64); a5 += __shfl_xor(a5, 32, 64);
            a6 += __shfl_xor(a6, 16, 64); a6 += __shfl_xor(a6, 32, 64);
            a7 += __shfl_xor(a7, 16, 64); a7 += __shfl_xor(a7, 32, 64);
            if (qw == 0) {
                float ds = sds[lr];
                float sc = (s == STEPS - 1) ? ds : ds * ds;
                u64 lo = (u64)pk(a0 * sc, a1 * sc) | ((u64)pk(a2 * sc, a3 * sc) << 32);
                u64 hi = (u64)pk(a4 * sc, a5 * sc) | ((u64)pk(a6 * sc, a7 * sc) << 32);
                u64* po = (u64*)(yb + row * C + l16 * 8);
                AST64(&po[0], lo);
                AST64(&po[1], hi);
            }
        }
        // s==1: bufA first-read next -> lite. s>=2: next phase re-reads lines
        // cached 2 steps ago -> maint (leader clean-L2-inv).
        if (s == 1) gsync_lite (bar, ph++, sid, xcd, scnt, sact, xact);
        else        gsync_maint(bar, ph++, sid, xcd, scnt, sact, xact);
        ushort* t = xb; xb = yb; yb = t;            // xb = just-written buffer
    }

    // ---- loss partials (plain cached loads; safe after last maint) ----
    {
        const ushort* x = xb;                        // final embeddings
        float sumP = 0.0f, sumN = 0.0f;
        int g    = lane >> 2;
        int q    = lane & 3;
        int wave = bid * 4 + wid;
        for (int base = wave * 16; base < E_TOTAL; base += BLOCKS * 4 * 16) {
            int e = base + g;
            int sI = ei[e];
            int tI = ei[E_TOTAL + e];
            const uint4* ps = (const uint4*)(x + sI * C + q * 32);
            const uint4* pt = (const uint4*)(x + tI * C + q * 32);
            uint4 s0 = ps[0], s1 = ps[1], s2 = ps[2], s3 = ps[3];
            uint4 t0 = pt[0], t1 = pt[1], t2 = pt[2], t3 = pt[3];
            float p = dot_u(s0.x, t0.x) + dot_u(s0.y, t0.y) + dot_u(s0.z, t0.z) + dot_u(s0.w, t0.w)
                    + dot_u(s1.x, t1.x) + dot_u(s1.y, t1.y) + dot_u(s1.z, t1.z) + dot_u(s1.w, t1.w)
                    + dot_u(s2.x, t2.x) + dot_u(s2.y, t2.y) + dot_u(s2.z, t2.z) + dot_u(s2.w, t2.w)
                    + dot_u(s3.x, t3.x) + dot_u(s3.y, t3.y) + dot_u(s3.z, t3.z) + dot_u(s3.w, t3.w);
            p += __shfl_xor(p, 1, 64);
            p += __shfl_xor(p, 2, 64);
            if (q == 0) sumP += log_sigmoid(p * INV_TEMP);
        }
        for (int base = wave * 16; base < N; base += BLOCKS * 4 * 16) {
            int i = base + g;
            int tI = ridx[i];
            const uint4* ps = (const uint4*)(x + i * C + q * 32);
            const uint4* pt = (const uint4*)(x + tI * C + q * 32);
            uint4 s0 = ps[0], s1 = ps[1], s2 = ps[2], s3 = ps[3];
            uint4 t0 = pt[0], t1 = pt[1], t2 = pt[2], t3 = pt[3];
            float p = dot_u(s0.x, t0.x) + dot_u(s0.y, t0.y) + dot_u(s0.z, t0.z) + dot_u(s0.w, t0.w)
                    + dot_u(s1.x, t1.x) + dot_u(s1.y, t1.y) + dot_u(s1.z, t1.z) + dot_u(s1.w, t1.w)
                    + dot_u(s2.x, t2.x) + dot_u(s2.y, t2.y) + dot_u(s2.z, t2.z) + dot_u(s2.w, t2.w)
                    + dot_u(s3.x, t3.x) + dot_u(s3.y, t3.y) + dot_u(s3.z, t3.z) + dot_u(s3.w, t3.w);
            p += __shfl_xor(p, 1, 64);
            p += __shfl_xor(p, 2, 64);
            if (q == 0) sumN += log_sigmoid(-p * INV_TEMP);
        }
        float v = sumP * (-1.0f / (float)E_TOTAL) + sumN * (-1.0f / (float)N);
        v += __shfl_xor(v, 4, 64);
        v += __shfl_xor(v, 8, 64);
        v += __shfl_xor(v, 16, 64);
        v += __shfl_xor(v, 32, 64);
        if (lane == 0) red[wid] = v;
        __syncthreads();
        if (tid == 0) {
            AST(&part[bid], (red[0] + red[1]) + (red[2] + red[3]));  // -> LLC
            drain_vmem();
            AADD(&bar[L_PDONE]);     // arrival; only block 0 waits
        }
    }

    // ---- block 0: wait for all partials, reduce, write scalar ----
    if (bid == 0) {
        if (tid == 0) {
            while (ALD(&bar[L_PDONE]) < (uint)BLOCKS) __builtin_amdgcn_s_sleep(1);
            __builtin_amdgcn_fence(__ATOMIC_ACQUIRE, "workgroup");
        }
        __syncthreads();
        // part lines never previously cached by block 0 -> plain reads fresh
        float s = part[tid] + part[tid + 256] + part[tid + 512] + part[tid + 768];
        red[tid] = s;
        __syncthreads();
        for (int off = 128; off > 0; off >>= 1) {
            if (tid < off) red[tid] += red[tid + off];
            __syncthreads();
        }
        if (tid == 0) out[0] = red[0];
    }
}

// ============================================================================
// Fallback: proven multi-kernel path (if cooperative launch is rejected).
// ============================================================================
__global__ void scatter_edges_kernel(const int* __restrict__ ei,
                                     unsigned int* __restrict__ bm,
                                     ushort* __restrict__ bufA,
                                     ushort* __restrict__ bufB) {
    int tid = threadIdx.x;
    if (blockIdx.x < 2 && tid < 16) {
        ushort* zr = (blockIdx.x == 0) ? bufA : bufB;
        uint4 z; z.x = 0; z.y = 0; z.z = 0; z.w = 0;
        ((uint4*)(zr + (size_t)ZROW * C))[tid] = z;
    }
    int e = blockIdx.x * blockDim.x + tid;
    if (e >= E_TOTAL) return;
    int s = ei[e];
    int t = ei[E_TOTAL + e];
    atomicOr(&bm[s * WPR + (t >> 5)], 1u << (t & 31));
}

__global__ void build_ell_kernel(const unsigned int* __restrict__ bm,
                                 int* __restrict__ cnt,
                                 int* __restrict__ ellc,
                                 float* __restrict__ dinvs) {
    int wid  = threadIdx.x >> 6;
    int lane = threadIdx.x & 63;
    int row  = blockIdx.x * 4 + wid;
    const unsigned int* p = bm + row * WPR;
    unsigned int w[4];
    int c = 0;
    for (int i = 0; i < 4; ++i) { w[i] = p[lane * 4 + i]; c += __popc(w[i]); }
    int inc = c;
    for (int off = 1; off < 64; off <<= 1) {
        int v = __shfl_up(inc, off, 64);
        if (lane >= off) inc += v;
    }
    int pos = inc - c;
    int total = __shfl(inc, 63, 64);
    for (int i = 0; i < 4; ++i) {
        unsigned int word = w[i];
        int jbase = (lane * 4 + i) << 5;
        while (word) {
            int b = __ffs(word) - 1;
            word &= word - 1;
            if (pos < S_ELL) ellc[row * S_ELL + pos] = jbase + b;
            ++pos;
        }
    }
    int ncap = (total < S_ELL) ? total : S_ELL;
    int npad = (ncap + 7) & ~7;
    if (lane < npad - ncap)
        ellc[row * S_ELL + ncap + lane] = ZROW;
    if (lane == 0) {
        cnt[row] = ncap;
        dinvs[row] = rsqrtf((float)total);
    }
}

__global__ __launch_bounds__(256) void spmm_step_kernel(
        const int* __restrict__ cnt, const int* __restrict__ ellc,
        const float* __restrict__ dinvs, const void* __restrict__ xin,
        ushort* __restrict__ y, int first, int last) {
    __shared__ int   scol[4 * S_ELL];
    __shared__ int   sn[4];
    __shared__ float ssc[4];
    const int tid  = threadIdx.x;
    const int wid  = tid >> 6;
    const int lane = tid & 63;
    const int qw   = lane >> 4;
    const int l16  = lane & 15;

    for (int i = tid; i < 4 * S_ELL; i += 256)
        scol[i] = ellc[blockIdx.x * 4 * S_ELL + i];
    if (tid < 4) {
        int row = blockIdx.x * 4 + tid;
        sn[tid] = cnt[row];
        float ds = dinvs[row];
        ssc[tid] = last ? ds : ds * ds;
    }
    __syncthreads();

    int row = blockIdx.x * 4 + wid;
    int n = sn[wid];
    const int* cr = scol + wid * S_ELL;
    float a0=0.f,a1=0.f,a2=0.f,a3=0.f,a4=0.f,a5=0.f,a6=0.f,a7=0.f;
    if (first) {
        const float* x = (const float*)xin;
        for (int k = 0; k < n; k += 8) {
            int i0 = k + qw, i1 = k + 4 + qw;
            int   c0 = (i0 < n) ? cr[i0] : row;
            int   c1 = (i1 < n) ? cr[i1] : row;
            float w0 = (i0 < n) ? dinvs[c0] : 0.0f;
            float w1 = (i1 < n) ? dinvs[c1] : 0.0f;
            const float* r0 = x + c0 * C + l16 * 8;
            const float* r1 = x + c1 * C + l16 * 8;
            float4 ua = *(const float4*)r0, ub = *(const float4*)(r0 + 4);
            float4 va = *(const float4*)r1, vb = *(const float4*)(r1 + 4);
            a0 += w0 * ua.x + w1 * va.x;  a1 += w0 * ua.y + w1 * va.y;
            a2 += w0 * ua.z + w1 * va.z;  a3 += w0 * ua.w + w1 * va.w;
            a4 += w0 * ub.x + w1 * vb.x;  a5 += w0 * ub.y + w1 * vb.y;
            a6 += w0 * ub.z + w1 * vb.z;  a7 += w0 * ub.w + w1 * vb.w;
        }
    } else {
        const ushort* x = (const ushort*)xin;
        int npad = (n + 7) & ~7;
        for (int k = 0; k < npad; k += 8) {
            int c0 = cr[k + qw];
            int c1 = cr[k + 4 + qw];
            uint4 u0 = *(const uint4*)(x + c0 * C + l16 * 8);
            uint4 u1 = *(const uint4*)(x + c1 * C + l16 * 8);
            a0 += bflo(u0.x) + bflo(u1.x);  a1 += bfhi(u0.x) + bfhi(u1.x);
            a2 += bflo(u0.y) + bflo(u1.y);  a3 += bfhi(u0.y) + bfhi(u1.y);
            a4 += bflo(u0.z) + bflo(u1.z);  a5 += bfhi(u0.z) + bfhi(u1.z);
            a6 += bflo(u0.w) + bflo(u1.w);  a7 += bfhi(u0.w) + bfhi(u1.w);
        }
    }
    a0 += __shfl_xor(a0, 16, 64); a0 += __shfl_xor(a0, 32, 64);
    a1 += __shfl_xor(a1, 16, 64); a1 += __shfl_xor(a1, 32, 64);
    a2 += __shfl_xor(a2, 16, 64); a2 += __shfl_xor(a2, 32, 64);
    a3 += __shfl_xor(a3, 16, 64); a3 += __shfl_xor(a3, 32, 64);
    a4 += __shfl_xor(a4, 16, 64); a4 += __shfl_xor(a4, 32, 64);
    a5 += __shfl_xor(a5, 16, 64); a5 += __shfl_xor(a5, 32, 64);
    a6 += __shfl_xor(a6, 16, 64); a6 += __shfl_xor(a6, 32, 64);
    a7 += __shfl_xor(a7, 16, 64); a7 += __shfl_xor(a7, 32, 64);
    if (qw == 0) {
        float sc = ssc[wid];
        uint4 o;
        o.x = (uint)f2bf(a0 * sc) | ((uint)f2bf(a1 * sc) << 16);
        o.y = (uint)f2bf(a2 * sc) | ((uint)f2bf(a3 * sc) << 16);
        o.z = (uint)f2bf(a4 * sc) | ((uint)f2bf(a5 * sc) << 16);
        o.w = (uint)f2bf(a6 * sc) | ((uint)f2bf(a7 * sc) << 16);
        *(uint4*)(y + row * C + l16 * 8) = o;
    }
}

__global__ void loss_kernel(const ushort* __restrict__ x,
                            const int* __restrict__ ei,
                            const int* __restrict__ ridx,
                            float* __restrict__ ppos,
                            float* __restrict__ pneg) {
    __shared__ float wsum[4];
    int lane = threadIdx.x & 63;
    int g    = lane >> 2;
    int q    = lane & 3;
    float sum = 0.0f;
    if (blockIdx.x < POS_BLOCKS) {
        int wave = (blockIdx.x * blockDim.x + threadIdx.x) >> 6;
        int nwaves = (POS_BLOCKS * 256) >> 6;
        for (int base = wave * 16; base < E_TOTAL; base += nwaves * 16) {
            int e = base + g;
            int s = ei[e];
            int t = ei[E_TOTAL + e];
            const uint4* ps = (const uint4*)(x + s * C + q * 32);
            const uint4* pt = (const uint4*)(x + t * C + q * 32);
            uint4 s0 = ps[0], s1 = ps[1], s2 = ps[2], s3 = ps[3];
            uint4 t0 = pt[0], t1 = pt[1], t2 = pt[2], t3 = pt[3];
            float p = dot_u(s0.x, t0.x) + dot_u(s0.y, t0.y) + dot_u(s0.z, t0.z) + dot_u(s0.w, t0.w)
                    + dot_u(s1.x, t1.x) + dot_u(s1.y, t1.y) + dot_u(s1.z, t1.z) + dot_u(s1.w, t1.w)
                    + dot_u(s2.x, t2.x) + dot_u(s2.y, t2.y) + dot_u(s2.z, t2.z) + dot_u(s2.w, t2.w)
                    + dot_u(s3.x, t3.x) + dot_u(s3.y, t3.y) + dot_u(s3.z, t3.z) + dot_u(s3.w, t3.w);
            p += __shfl_xor(p, 1, 64);
            p += __shfl_xor(p, 2, 64);
            if (q == 0) sum += log_sigmoid(p * INV_TEMP);
        }
    } else {
        int bi = blockIdx.x - POS_BLOCKS;
        int wave = (bi * blockDim.x + threadIdx.x) >> 6;
        int nwaves = (NEG_BLOCKS * 256) >> 6;
        for (int base = wave * 16; base < N; base += nwaves * 16) {
            int i = base + g;
            int t = ridx[i];
            const uint4* ps = (const uint4*)(x + i * C + q * 32);
            const uint4* pt = (const uint4*)(x + t * C + q * 32);
            uint4 s0 = ps[0], s1 = ps[1], s2 = ps[2], s3 = ps[3];
            uint4 t0 = pt[0], t1 = pt[1], t2 = pt[2], t3 = pt[3];
            float p = dot_u(s0.x, t0.x) + dot_u(s0.y, t0.y) + dot_u(s0.z, t0.z) + dot_u(s0.w, t0.w)
                    + dot_u(s1.x, t1.x) + dot_u(s1.y, t1.y) + dot_u(s1.z, t1.z) + dot_u(s1.w, t1.w)
                    + dot_u(s2.x, t2.x) + dot_u(s2.y, t2.y) + dot_u(s2.z, t2.z) + dot_u(s2.w, t2.w)
                    + dot_u(s3.x, t3.x) + dot_u(s3.y, t3.y) + dot_u(s3.z, t3.z) + dot_u(s3.w, t3.w);
            p += __shfl_xor(p, 1, 64);
            p += __shfl_xor(p, 2, 64);
            if (q == 0) sum += log_sigmoid(-p * INV_TEMP);
        }
    }
    sum += __shfl_xor(sum, 4, 64);
    sum += __shfl_xor(sum, 8, 64);
    sum += __shfl_xor(sum, 16, 64);
    sum += __shfl_xor(sum, 32, 64);
    if (lane == 0) wsum[threadIdx.x >> 6] = sum;
    __syncthreads();
    if (threadIdx.x == 0) {
        float v = (wsum[0] + wsum[1]) + (wsum[2] + wsum[3]);
        if (blockIdx.x < POS_BLOCKS) ppos[blockIdx.x] = v;
        else                         pneg[blockIdx.x - POS_BLOCKS] = v;
    }
}

__global__ void finalize_kernel(const float* __restrict__ ppos,
                                const float* __restrict__ pneg,
                                float* __restrict__ out) {
    __shared__ float red[256];
    int t = threadIdx.x;
    float s = 0.0f;
    for (int i = t; i < POS_BLOCKS; i += 256) s += ppos[i];
    float sn = (t < NEG_BLOCKS) ? pneg[t] : 0.0f;
    red[t] = s * (-1.0f / (float)E_TOTAL) + sn * (-1.0f / (float)N);
    __syncthreads();
    for (int off = 128; off > 0; off >>= 1) {
        if (t < off) red[t] += red[t + off];
        __syncthreads();
    }
    if (t == 0) out[0] = red[0];
}

extern "C" void kernel_launch(void* const* d_in, const int* in_sizes, int n_in,
                              void* d_out, int out_size, void* d_ws, size_t ws_size,
                              hipStream_t stream) {
    (void)in_sizes; (void)n_in; (void)out_size; (void)ws_size;

    const float* emb_in = (const float*)d_in[0];
    const int*   ei     = (const int*)d_in[1];   // (2, E) flattened: src then dst
    const int*   ridx   = (const int*)d_in[2];
    float* out = (float*)d_out;

    char* ws = (char*)d_ws;
    uint*         bar   = (uint*)(ws + OFF_BAR);
    unsigned int* bm    = (unsigned int*)(ws + OFF_BITMAP);
    float*        dinvs = (float*)(ws + OFF_DINV);
    int*          cnt   = (int*)(ws + OFF_CNT);
    float*        part  = (float*)(ws + OFF_PART);
    float*        pneg  = (float*)(ws + OFF_PNEG);
    int*          ellc  = (int*)(ws + OFF_ELL);
    ushort*       bufA  = (ushort*)(ws + OFF_BUFA);
    ushort*       bufB  = (ushort*)(ws + OFF_BUFB);

    // one memset zeroes barrier state + dedup bitmap (contiguous, r4-proven)
    hipMemsetAsync(ws + OFF_BAR, 0, BAR_BYTES + BITMAP_BYTES, stream);

    void* args[] = { (void*)&emb_in, (void*)&ei, (void*)&ridx, (void*)&dinvs,
                     (void*)&part,   (void*)&bm, (void*)&bar,  (void*)&bufA,
                     (void*)&bufB,   (void*)&out };
    hipError_t rc = hipLaunchCooperativeKernel(
        reinterpret_cast<void*>(mega_kernel),
        dim3(BLOCKS), dim3(256), args, 0, stream);

    if (rc != hipSuccess) {
        // Fallback: proven multi-kernel path (bitmap already zeroed above).
        ushort* buf[2] = {bufA, bufB};
        scatter_edges_kernel<<<E_TOTAL / 256, 256, 0, stream>>>(ei, bm, bufA, bufB);
        build_ell_kernel<<<N / 4, 256, 0, stream>>>(bm, cnt, ellc, dinvs);
        for (int s = 0; s < STEPS; ++s) {
            const void* xs = (s == 0) ? (const void*)emb_in : (const void*)buf[s & 1];
            ushort* yd = buf[(s + 1) & 1];
            spmm_step_kernel<<<N / 4, 256, 0, stream>>>(cnt, ellc, dinvs, xs, yd,
                                                        s == 0 ? 1 : 0,
                                                        s == STEPS - 1 ? 1 : 0);
        }
        const ushort* emb = buf[STEPS & 1];
        loss_kernel<<<POS_BLOCKS + NEG_BLOCKS, 256, 0, stream>>>(emb, ei, ridx, part, pneg);
        finalize_kernel<<<1, 256, 0, stream>>>(part, pneg, out);
    }
}

// Round 7
// 217.786 us; speedup vs baseline: 1.4874x; 1.0477x over previous
//
#include <hip/hip_runtime.h>
#include <math.h>

// Problem constants (from reference)
#define N        8192
#define C        128
#define E_TOTAL  262144
#define WPR      256          // bitmap words per row = N/32
#define INV_TEMP 2.0f         // 1/0.5
#define STEPS    10
#define S_ELL    96           // max dedup'd neighbors per row
#define ZROW     N            // zero row in bf16 buffers (row N kept zero)
#define POS_BLOCKS 2048
#define NEG_BLOCKS 128
#define BLOCKS   256          // persistent grid: 1 block/CU on 256 CUs
#define THREADS  1024         // 16 waves/block; 32 rows/block
#define RPB      32           // rows per block
#define NWAVES   (BLOCKS * 16)
#define NG       32           // groups for the bootstrap barrier
#define GSZ      (BLOCKS / NG)
#define NXCD     8

// ---- workspace layout (bytes) ----
// bar + bitmap contiguous so ONE hipMemsetAsync zeroes both (r4-proven).
#define OFF_BAR     0                             // 32 KB barrier state
#define BAR_BYTES   32768
#define OFF_BITMAP  BAR_BYTES                     // 8 MB
#define BITMAP_BYTES (N * WPR * 4)
#define OFF_DINV    (OFF_BITMAP + BITMAP_BYTES)   // float dinvs[N]   32 KB
#define OFF_CNT     (OFF_DINV + 32768)            // int   cnt[N]     32 KB (fallback)
#define OFF_PART    (OFF_CNT + 32768)             // float part[2048] 8 KB
#define OFF_PNEG    (OFF_PART + 8192)             // float pneg[128]  1 KB (fallback)
#define OFF_ELL     (OFF_PNEG + 1024)             // int   ellc[N*96] 3 MB (fallback)
#define OFF_BUFA    (OFF_ELL + N * S_ELL * 4)     // bf16 (N+1)*C
#define OFF_BUFB    (OFF_BUFA + (N + 1) * C * 2)  // bf16 (N+1)*C

// ---- barrier state (uint index; one counter per 32-uint = 128 B line) ----
#define L_BGC(g)    ((g) * 32)           // bootstrap group counters   (0..31)
#define L_BRC       (32 * 32)            // bootstrap root counter
#define L_BF(g)     ((33 + (g)) * 32)    // bootstrap release flags
#define L_SARR(i)   ((65 + (i)) * 32)    // sub arrive counters (32)
#define L_XARR(x)   ((97 + (x)) * 32)    // per-XCD arrive counters (8)
#define L_XROOT     (105 * 32)           // root arrive counter
#define L_XFLAG(x)  ((106 + (x)) * 32)   // per-XCD release flags (root-set)
#define L_XFLAG2(x) ((114 + (x)) * 32)   // per-XCD "L2 inv done" flags
#define L_SCNT(i)   ((122 + (i)) * 32)   // per-sub registration counts
#define L_PDONE     (154 * 32)           // loss-partials-done counter

// s_getreg imm for HW_REG_XCC_ID (id=20, offset=0, size=32): ((32-1)<<11)|20
#define XCC_ID_IMM 63508

typedef unsigned int        uint;
typedef unsigned short      ushort;
typedef unsigned long long  u64;

#define ALD(p)    __hip_atomic_load((p), __ATOMIC_RELAXED, __HIP_MEMORY_SCOPE_AGENT)
#define AST(p, v) __hip_atomic_store((p), (v), __ATOMIC_RELAXED, __HIP_MEMORY_SCOPE_AGENT)
#define AADD(p)   __hip_atomic_fetch_add((p), 1u, __ATOMIC_RELAXED, __HIP_MEMORY_SCOPE_AGENT)

__device__ __forceinline__ float bflo(uint u) { return __uint_as_float(u << 16); }
__device__ __forceinline__ float bfhi(uint u) { return __uint_as_float(u & 0xffff0000u); }
__device__ __forceinline__ ushort f2bf(float f) {   // RNE
    uint u = __float_as_uint(f);
    return (ushort)((u + 0x7fffu + ((u >> 16) & 1u)) >> 16);
}
__device__ __forceinline__ float dot_u(uint a, uint b) {
    return bflo(a) * bflo(b) + bfhi(a) * bfhi(b);
}
__device__ __forceinline__ float log_sigmoid(float z) {
    return fminf(z, 0.0f) - log1pf(expf(-fabsf(z)));
}
__device__ __forceinline__ void drain_vmem() {
    asm volatile("s_waitcnt vmcnt(0)" ::: "memory");
}

// ---------------------------------------------------------------------------
// Bootstrap barrier (used once, after scatter): per-block full release fence
// (r2/r4-proven), counter tree, relaxed flags. 8 blocks/group -> short chains.
// ---------------------------------------------------------------------------
__device__ __forceinline__ void gsync_boot(uint* bar, uint g) {
    __syncthreads();
    if (threadIdx.x == 0) {
        __threadfence();                        // release: scatter atomics done
        uint old = AADD(&bar[L_BGC(g)]);
        if (old == GSZ - 1u) {
            uint ro = AADD(&bar[L_BRC]);
            if (ro == NG - 1u) {
                #pragma unroll
                for (uint i = 0; i < NG; ++i) AST(&bar[L_BF(i)], 1u);
            }
        }
        while (ALD(&bar[L_BF(g)]) < 1u) __builtin_amdgcn_s_sleep(1);
        __builtin_amdgcn_fence(__ATOMIC_ACQUIRE, "agent");
    }
    __syncthreads();
}

// ---------------------------------------------------------------------------
// r4-proven XCD-hierarchical barrier, now with 4x fewer participants:
// arrive sub(8 blocks, relaxed) -> XCD(4 subs, relaxed) -> root (RELEASE:
// one buffer_wbl2 per XCD, issued by that XCD's last arriver). Root-last
// publishes XFLAG. Each XCD leader does the SINGLE agent-acquire (one L2
// inv per XCD) and publishes XFLAG2; followers L1-inv only. Monotone
// counters, no resets; dynamic registration counts keep it hang-safe for
// any block->XCD distribution.
// ---------------------------------------------------------------------------
__device__ __forceinline__ void gsyncx(uint* bar, uint phase, uint sid, uint xcd,
                                       uint scnt, uint sact, uint xact) {
    drain_vmem();
    __syncthreads();
    if (threadIdx.x == 0) {
        bool leader = false;
        uint so = AADD(&bar[L_SARR(sid)]);
        if (so == phase * scnt - 1u) {          // last block of this sub-bucket
            uint xo = AADD(&bar[L_XARR(xcd)]);
            if (xo == phase * sact - 1u) {      // last sub of this XCD
                leader = true;
                uint ro = __hip_atomic_fetch_add(&bar[L_XROOT], 1u,
                                                 __ATOMIC_RELEASE, __HIP_MEMORY_SCOPE_AGENT);
                if (ro == phase * xact - 1u) {  // last XCD overall
                    #pragma unroll
                    for (uint x = 0; x < NXCD; ++x) AST(&bar[L_XFLAG(x)], phase);
                }
            }
        }
        if (leader) {
            while (ALD(&bar[L_XFLAG(xcd)]) < phase) __builtin_amdgcn_s_sleep(1);
            __builtin_amdgcn_fence(__ATOMIC_ACQUIRE, "agent");   // ONE L2 inv / XCD
            AST(&bar[L_XFLAG2(xcd)], phase);
        } else {
            while (ALD(&bar[L_XFLAG2(xcd)]) < phase) __builtin_amdgcn_s_sleep(1);
            asm volatile("buffer_inv sc0\n\t"
                         "s_waitcnt vmcnt(0)" ::: "memory");     // own-CU L1 only
        }
        __builtin_amdgcn_fence(__ATOMIC_ACQUIRE, "workgroup");
    }
    __syncthreads();
}

// ============================================================================
// Persistent mega-kernel: 256 blocks x 1024 threads (16 waves), 32 rows per
// block, wave owns 2 rows; ELL lists live in LDS throughout. r4 data path
// (cached b128 gathers, cached uint4 stores). 4x fewer barrier participants.
// ============================================================================
__global__ __launch_bounds__(1024, 4) void mega_kernel(
        const float* __restrict__ emb,
        const int*   __restrict__ ei,
        const int*   __restrict__ ridx,
        float*       __restrict__ dinvs,
        float*       __restrict__ part,
        unsigned int* __restrict__ bm,
        uint*        __restrict__ bar,
        ushort*      __restrict__ bufA,
        ushort*      __restrict__ bufB,
        float*       __restrict__ out)
{
    __shared__ int   scol[RPB * S_ELL];   // 12 KB: per-block ELL cols
    __shared__ int   sn[RPB];
    __shared__ float sds[RPB];
    __shared__ float red[256];

    const int  tid  = threadIdx.x;
    const int  bid  = blockIdx.x;
    const int  wid  = tid >> 6;           // 0..15
    const int  lane = tid & 63;
    const int  qw   = lane >> 4;
    const int  l16  = lane & 15;
    const int  gtid = bid * THREADS + tid;   // exactly one edge per thread
    const uint xcd  = __builtin_amdgcn_s_getreg(XCC_ID_IMM) & 7u;
    const uint sid  = xcd * 4u + (uint)(bid & 3);
    const uint bg   = (uint)(bid & (NG - 1));

    // ---- register this block's (xcd, sub) bucket ----
    if (tid == 0) AADD(&bar[L_SCNT(sid)]);

    // ---- phase: scatter edges (one edge/thread) + zero row ZROW ----
    {
        if (bid == 0 && tid < 32) {
            ushort* zr = (tid < 16) ? bufA : bufB;
            uint4 z; z.x = 0; z.y = 0; z.z = 0; z.w = 0;
            ((uint4*)(zr + (size_t)ZROW * C))[tid & 15] = z;
        }
        int s = ei[gtid];
        int t = ei[E_TOTAL + gtid];
        atomicOr(&bm[s * WPR + (t >> 5)], 1u << (t & 31));
    }
    gsync_boot(bar, bg);

    // ---- bucket counts frozen: derive thresholds (tid0 only) ----
    uint scnt = 1, sact = 1, xact = 1;
    if (tid == 0) {
        xact = 0;
        #pragma unroll
        for (uint x = 0; x < NXCD; ++x) {
            uint nz = 0;
            #pragma unroll
            for (uint s2 = 0; s2 < 4; ++s2) {
                uint c = ALD(&bar[L_SCNT(x * 4u + s2)]);
                nz += (c != 0u);
                if (x * 4u + s2 == sid) scnt = (c ? c : 1u);
            }
            if (x == xcd) sact = (nz ? nz : 1u);
            xact += (nz != 0u);
        }
        if (xact == 0u) xact = 1u;
    }
    uint ph = 1;

    // ---- build ELL into LDS (wave -> 2 rows) + global dinvs ----
    for (int rr = 0; rr < 2; ++rr) {
        int lr  = wid * 2 + rr;                   // 0..31
        int row = bid * RPB + lr;
        const unsigned int* p = bm + row * WPR;
        unsigned int w[4];
        int c = 0;
        #pragma unroll
        for (int i = 0; i < 4; ++i) { w[i] = p[lane * 4 + i]; c += __popc(w[i]); }
        int inc = c;
        for (int off = 1; off < 64; off <<= 1) {
            int v = __shfl_up(inc, off, 64);
            if (lane >= off) inc += v;
        }
        int pos = inc - c;
        int total = __shfl(inc, 63, 64);
        for (int i = 0; i < 4; ++i) {
            unsigned int word = w[i];
            int jbase = (lane * 4 + i) << 5;
            while (word) {
                int b = __ffs(word) - 1;
                word &= word - 1;
                if (pos < S_ELL) scol[lr * S_ELL + pos] = jbase + b;
                ++pos;
            }
        }
        int ncap = (total < S_ELL) ? total : S_ELL;
        int npad = (ncap + 7) & ~7;                 // <= 96
        if (lane < npad - ncap)                     // pad -> zero row
            scol[lr * S_ELL + ncap + lane] = ZROW;
        if (lane == 0) {
            sn[lr]  = ncap;
            float ds = rsqrtf((float)total);        // deg >= 1 (self-loops)
            sds[lr] = ds;
            dinvs[row] = ds;
        }
    }
    gsyncx(bar, ph++, sid, xcd, scnt, sact, xact);   // dinvs globally visible

    // ---- diffusion step 0 (fp32 input, gather weight dinvs[j]) ----
    for (int rr = 0; rr < 2; ++rr) {
        int lr  = wid * 2 + rr;
        int row = bid * RPB + lr;
        int n   = sn[lr];
        const int* cr = scol + lr * S_ELL;
        float a0=0.f,a1=0.f,a2=0.f,a3=0.f,a4=0.f,a5=0.f,a6=0.f,a7=0.f;
        for (int k = 0; k < n; k += 8) {
            int i0 = k + qw, i1 = k + 4 + qw;
            int   c0 = (i0 < n) ? cr[i0] : row;
            int   c1 = (i1 < n) ? cr[i1] : row;
            float w0 = (i0 < n) ? dinvs[c0] : 0.0f;
            float w1 = (i1 < n) ? dinvs[c1] : 0.0f;
            const float* r0 = emb + c0 * C + l16 * 8;
            const float* r1 = emb + c1 * C + l16 * 8;
            float4 ua = *(const float4*)r0, ub = *(const float4*)(r0 + 4);
            float4 va = *(const float4*)r1, vb = *(const float4*)(r1 + 4);
            a0 += w0 * ua.x + w1 * va.x;  a1 += w0 * ua.y + w1 * va.y;
            a2 += w0 * ua.z + w1 * va.z;  a3 += w0 * ua.w + w1 * va.w;
            a4 += w0 * ub.x + w1 * vb.x;  a5 += w0 * ub.y + w1 * vb.y;
            a6 += w0 * ub.z + w1 * vb.z;  a7 += w0 * ub.w + w1 * vb.w;
        }
        a0 += __shfl_xor(a0, 16, 64); a0 += __shfl_xor(a0, 32, 64);
        a1 += __shfl_xor(a1, 16, 64); a1 += __shfl_xor(a1, 32, 64);
        a2 += __shfl_xor(a2, 16, 64); a2 += __shfl_xor(a2, 32, 64);
        a3 += __shfl_xor(a3, 16, 64); a3 += __shfl_xor(a3, 32, 64);
        a4 += __shfl_xor(a4, 16, 64); a4 += __shfl_xor(a4, 32, 64);
        a5 += __shfl_xor(a5, 16, 64); a5 += __shfl_xor(a5, 32, 64);
        a6 += __shfl_xor(a6, 16, 64); a6 += __shfl_xor(a6, 32, 64);
        a7 += __shfl_xor(a7, 16, 64); a7 += __shfl_xor(a7, 32, 64);
        if (qw == 0) {
            float ds = sds[lr];
            float sc = ds * ds;                     // step 0 is never last
            uint4 o;
            o.x = (uint)f2bf(a0 * sc) | ((uint)f2bf(a1 * sc) << 16);
            o.y = (uint)f2bf(a2 * sc) | ((uint)f2bf(a3 * sc) << 16);
            o.z = (uint)f2bf(a4 * sc) | ((uint)f2bf(a5 * sc) << 16);
            o.w = (uint)f2bf(a6 * sc) | ((uint)f2bf(a7 * sc) << 16);
            *(uint4*)(bufB + row * C + l16 * 8) = o;
        }
    }
    gsyncx(bar, ph++, sid, xcd, scnt, sact, xact);

    // ---- steps 1..9 (bf16 ping-pong; cached b128 gathers) ----
    ushort* xb = bufB;
    ushort* yb = bufA;
    for (int s = 1; s < STEPS; ++s) {
        for (int rr = 0; rr < 2; ++rr) {
            int lr  = wid * 2 + rr;
            int row = bid * RPB + lr;
            int n   = sn[lr];
            int npad = (n + 7) & ~7;                // ZROW-padded; row ZROW zero
            const int* cr = scol + lr * S_ELL;
            float a0=0.f,a1=0.f,a2=0.f,a3=0.f,a4=0.f,a5=0.f,a6=0.f,a7=0.f;
            for (int k = 0; k < npad; k += 8) {
                int c0 = cr[k + qw];
                int c1 = cr[k + 4 + qw];
                uint4 u0 = *(const uint4*)(xb + c0 * C + l16 * 8);
                uint4 u1 = *(const uint4*)(xb + c1 * C + l16 * 8);
                a0 += bflo(u0.x) + bflo(u1.x);  a1 += bfhi(u0.x) + bfhi(u1.x);
                a2 += bflo(u0.y) + bflo(u1.y);  a3 += bfhi(u0.y) + bfhi(u1.y);
                a4 += bflo(u0.z) + bflo(u1.z);  a5 += bfhi(u0.z) + bfhi(u1.z);
                a6 += bflo(u0.w) + bflo(u1.w);  a7 += bfhi(u0.w) + bfhi(u1.w);
            }
            a0 += __shfl_xor(a0, 16, 64); a0 += __shfl_xor(a0, 32, 64);
            a1 += __shfl_xor(a1, 16, 64); a1 += __shfl_xor(a1, 32, 64);
            a2 += __shfl_xor(a2, 16, 64); a2 += __shfl_xor(a2, 32, 64);
            a3 += __shfl_xor(a3, 16, 64); a3 += __shfl_xor(a3, 32, 64);
            a4 += __shfl_xor(a4, 16, 64); a4 += __shfl_xor(a4, 32, 64);
            a5 += __shfl_xor(a5, 16, 64); a5 += __shfl_xor(a5, 32, 64);
            a6 += __shfl_xor(a6, 16, 64); a6 += __shfl_xor(a6, 32, 64);
            a7 += __shfl_xor(a7, 16, 64); a7 += __shfl_xor(a7, 32, 64);
            if (qw == 0) {
                float ds = sds[lr];
                float sc = (s == STEPS - 1) ? ds : ds * ds;
                uint4 o;
                o.x = (uint)f2bf(a0 * sc) | ((uint)f2bf(a1 * sc) << 16);
                o.y = (uint)f2bf(a2 * sc) | ((uint)f2bf(a3 * sc) << 16);
                o.z = (uint)f2bf(a4 * sc) | ((uint)f2bf(a5 * sc) << 16);
                o.w = (uint)f2bf(a6 * sc) | ((uint)f2bf(a7 * sc) << 16);
                *(uint4*)(yb + row * C + l16 * 8) = o;
            }
        }
        gsyncx(bar, ph++, sid, xcd, scnt, sact, xact);
        ushort* t = xb; xb = yb; yb = t;            // xb = just-written buffer
    }

    // ---- loss partials (per-block; 16 waves) ----
    {
        const ushort* x = xb;                        // final embeddings
        float sumP = 0.0f, sumN = 0.0f;
        int g    = lane >> 2;   // 16 items per wave-iteration
        int q    = lane & 3;    // 4 lanes per item, 32 channels each
        int wave = bid * 16 + wid;                   // 0..4095
        for (int base = wave * 16; base < E_TOTAL; base += NWAVES * 16) {
            int e = base + g;
            int sI = ei[e];
            int tI = ei[E_TOTAL + e];
            const uint4* ps = (const uint4*)(x + sI * C + q * 32);
            const uint4* pt = (const uint4*)(x + tI * C + q * 32);
            uint4 s0 = ps[0], s1 = ps[1], s2 = ps[2], s3 = ps[3];
            uint4 t0 = pt[0], t1 = pt[1], t2 = pt[2], t3 = pt[3];
            float p = dot_u(s0.x, t0.x) + dot_u(s0.y, t0.y) + dot_u(s0.z, t0.z) + dot_u(s0.w, t0.w)
                    + dot_u(s1.x, t1.x) + dot_u(s1.y, t1.y) + dot_u(s1.z, t1.z) + dot_u(s1.w, t1.w)
                    + dot_u(s2.x, t2.x) + dot_u(s2.y, t2.y) + dot_u(s2.z, t2.z) + dot_u(s2.w, t2.w)
                    + dot_u(s3.x, t3.x) + dot_u(s3.y, t3.y) + dot_u(s3.z, t3.z) + dot_u(s3.w, t3.w);
            p += __shfl_xor(p, 1, 64);
            p += __shfl_xor(p, 2, 64);
            if (q == 0) sumP += log_sigmoid(p * INV_TEMP);
        }
        for (int base = wave * 16; base < N; base += NWAVES * 16) {
            int i = base + g;
            int tI = ridx[i];
            const uint4* ps = (const uint4*)(x + i * C + q * 32);
            const uint4* pt = (const uint4*)(x + tI * C + q * 32);
            uint4 s0 = ps[0], s1 = ps[1], s2 = ps[2], s3 = ps[3];
            uint4 t0 = pt[0], t1 = pt[1], t2 = pt[2], t3 = pt[3];
            float p = dot_u(s0.x, t0.x) + dot_u(s0.y, t0.y) + dot_u(s0.z, t0.z) + dot_u(s0.w, t0.w)
                    + dot_u(s1.x, t1.x) + dot_u(s1.y, t1.y) + dot_u(s1.z, t1.z) + dot_u(s1.w, t1.w)
                    + dot_u(s2.x, t2.x) + dot_u(s2.y, t2.y) + dot_u(s2.z, t2.z) + dot_u(s2.w, t2.w)
                    + dot_u(s3.x, t3.x) + dot_u(s3.y, t3.y) + dot_u(s3.z, t3.z) + dot_u(s3.w, t3.w);
            p += __shfl_xor(p, 1, 64);
            p += __shfl_xor(p, 2, 64);
            if (q == 0) sumN += log_sigmoid(-p * INV_TEMP);
        }
        float v = sumP * (-1.0f / (float)E_TOTAL) + sumN * (-1.0f / (float)N);
        v += __shfl_xor(v, 4, 64);
        v += __shfl_xor(v, 8, 64);
        v += __shfl_xor(v, 16, 64);
        v += __shfl_xor(v, 32, 64);
        if (lane == 0) red[wid] = v;
        __syncthreads();
        if (tid == 0) {
            float t = 0.0f;
            #pragma unroll
            for (int i = 0; i < 16; ++i) t += red[i];
            AST(&part[bid], t);                      // write-through -> LLC
            drain_vmem();
            AADD(&bar[L_PDONE]);                     // arrival; only block 0 waits
        }
    }

    // ---- block 0: wait for all partials, reduce, write scalar ----
    if (bid == 0) {
        if (tid == 0) {
            while (ALD(&bar[L_PDONE]) < (uint)BLOCKS) __builtin_amdgcn_s_sleep(1);
            __builtin_amdgcn_fence(__ATOMIC_ACQUIRE, "workgroup");
        }
        __syncthreads();
        // part lines never previously cached by block 0 -> plain reads fresh
        if (tid < 256) red[tid] = part[tid];
        __syncthreads();
        for (int off = 128; off > 0; off >>= 1) {
            if (tid < off) red[tid] += red[tid + off];
            __syncthreads();
        }
        if (tid == 0) out[0] = red[0];
    }
}

// ============================================================================
// Fallback: proven multi-kernel path (if cooperative launch is rejected).
// ============================================================================
__global__ void scatter_edges_kernel(const int* __restrict__ ei,
                                     unsigned int* __restrict__ bm,
                                     ushort* __restrict__ bufA,
                                     ushort* __restrict__ bufB) {
    int tid = threadIdx.x;
    if (blockIdx.x < 2 && tid < 16) {
        ushort* zr = (blockIdx.x == 0) ? bufA : bufB;
        uint4 z; z.x = 0; z.y = 0; z.z = 0; z.w = 0;
        ((uint4*)(zr + (size_t)ZROW * C))[tid] = z;
    }
    int e = blockIdx.x * blockDim.x + tid;
    if (e >= E_TOTAL) return;
    int s = ei[e];
    int t = ei[E_TOTAL + e];
    atomicOr(&bm[s * WPR + (t >> 5)], 1u << (t & 31));
}

__global__ void build_ell_kernel(const unsigned int* __restrict__ bm,
                                 int* __restrict__ cnt,
                                 int* __restrict__ ellc,
                                 float* __restrict__ dinvs) {
    int wid  = threadIdx.x >> 6;
    int lane = threadIdx.x & 63;
    int row  = blockIdx.x * 4 + wid;
    const unsigned int* p = bm + row * WPR;
    unsigned int w[4];
    int c = 0;
    for (int i = 0; i < 4; ++i) { w[i] = p[lane * 4 + i]; c += __popc(w[i]); }
    int inc = c;
    for (int off = 1; off < 64; off <<= 1) {
        int v = __shfl_up(inc, off, 64);
        if (lane >= off) inc += v;
    }
    int pos = inc - c;
    int total = __shfl(inc, 63, 64);
    for (int i = 0; i < 4; ++i) {
        unsigned int word = w[i];
        int jbase = (lane * 4 + i) << 5;
        while (word) {
            int b = __ffs(word) - 1;
            word &= word - 1;
            if (pos < S_ELL) ellc[row * S_ELL + pos] = jbase + b;
            ++pos;
        }
    }
    int ncap = (total < S_ELL) ? total : S_ELL;
    int npad = (ncap + 7) & ~7;
    if (lane < npad - ncap)
        ellc[row * S_ELL + ncap + lane] = ZROW;
    if (lane == 0) {
        cnt[row] = ncap;
        dinvs[row] = rsqrtf((float)total);
    }
}

__global__ __launch_bounds__(256) void spmm_step_kernel(
        const int* __restrict__ cnt, const int* __restrict__ ellc,
        const float* __restrict__ dinvs, const void* __restrict__ xin,
        ushort* __restrict__ y, int first, int last) {
    __shared__ int   scol[4 * S_ELL];
    __shared__ int   sn[4];
    __shared__ float ssc[4];
    const int tid  = threadIdx.x;
    const int wid  = tid >> 6;
    const int lane = tid & 63;
    const int qw   = lane >> 4;
    const int l16  = lane & 15;

    for (int i = tid; i < 4 * S_ELL; i += 256)
        scol[i] = ellc[blockIdx.x * 4 * S_ELL + i];
    if (tid < 4) {
        int row = blockIdx.x * 4 + tid;
        sn[tid] = cnt[row];
        float ds = dinvs[row];
        ssc[tid] = last ? ds : ds * ds;
    }
    __syncthreads();

    int row = blockIdx.x * 4 + wid;
    int n = sn[wid];
    const int* cr = scol + wid * S_ELL;
    float a0=0.f,a1=0.f,a2=0.f,a3=0.f,a4=0.f,a5=0.f,a6=0.f,a7=0.f;
    if (first) {
        const float* x = (const float*)xin;
        for (int k = 0; k < n; k += 8) {
            int i0 = k + qw, i1 = k + 4 + qw;
            int   c0 = (i0 < n) ? cr[i0] : row;
            int   c1 = (i1 < n) ? cr[i1] : row;
            float w0 = (i0 < n) ? dinvs[c0] : 0.0f;
            float w1 = (i1 < n) ? dinvs[c1] : 0.0f;
            const float* r0 = x + c0 * C + l16 * 8;
            const float* r1 = x + c1 * C + l16 * 8;
            float4 ua = *(const float4*)r0, ub = *(const float4*)(r0 + 4);
            float4 va = *(const float4*)r1, vb = *(const float4*)(r1 + 4);
            a0 += w0 * ua.x + w1 * va.x;  a1 += w0 * ua.y + w1 * va.y;
            a2 += w0 * ua.z + w1 * va.z;  a3 += w0 * ua.w + w1 * va.w;
            a4 += w0 * ub.x + w1 * vb.x;  a5 += w0 * ub.y + w1 * vb.y;
            a6 += w0 * ub.z + w1 * vb.z;  a7 += w0 * ub.w + w1 * vb.w;
        }
    } else {
        const ushort* x = (const ushort*)xin;
        int npad = (n + 7) & ~7;
        for (int k = 0; k < npad; k += 8) {
            int c0 = cr[k + qw];
            int c1 = cr[k + 4 + qw];
            uint4 u0 = *(const uint4*)(x + c0 * C + l16 * 8);
            uint4 u1 = *(const uint4*)(x + c1 * C + l16 * 8);
            a0 += bflo(u0.x) + bflo(u1.x);  a1 += bfhi(u0.x) + bfhi(u1.x);
            a2 += bflo(u0.y) + bflo(u1.y);  a3 += bfhi(u0.y) + bfhi(u1.y);
            a4 += bflo(u0.z) + bflo(u1.z);  a5 += bfhi(u0.z) + bfhi(u1.z);
            a6 += bflo(u0.w) + bflo(u1.w);  a7 += bfhi(u0.w) + bfhi(u1.w);
        }
    }
    a0 += __shfl_xor(a0, 16, 64); a0 += __shfl_xor(a0, 32, 64);
    a1 += __shfl_xor(a1, 16, 64); a1 += __shfl_xor(a1, 32, 64);
    a2 += __shfl_xor(a2, 16, 64); a2 += __shfl_xor(a2, 32, 64);
    a3 += __shfl_xor(a3, 16, 64); a3 += __shfl_xor(a3, 32, 64);
    a4 += __shfl_xor(a4, 16, 64); a4 += __shfl_xor(a4, 32, 64);
    a5 += __shfl_xor(a5, 16, 64); a5 += __shfl_xor(a5, 32, 64);
    a6 += __shfl_xor(a6, 16, 64); a6 += __shfl_xor(a6, 32, 64);
    a7 += __shfl_xor(a7, 16, 64); a7 += __shfl_xor(a7, 32, 64);
    if (qw == 0) {
        float sc = ssc[wid];
        uint4 o;
        o.x = (uint)f2bf(a0 * sc) | ((uint)f2bf(a1 * sc) << 16);
        o.y = (uint)f2bf(a2 * sc) | ((uint)f2bf(a3 * sc) << 16);
        o.z = (uint)f2bf(a4 * sc) | ((uint)f2bf(a5 * sc) << 16);
        o.w = (uint)f2bf(a6 * sc) | ((uint)f2bf(a7 * sc) << 16);
        *(uint4*)(y + row * C + l16 * 8) = o;
    }
}

__global__ void loss_kernel(const ushort* __restrict__ x,
                            const int* __restrict__ ei,
                            const int* __restrict__ ridx,
                            float* __restrict__ ppos,
                            float* __restrict__ pneg) {
    __shared__ float wsum[4];
    int lane = threadIdx.x & 63;
    int g    = lane >> 2;
    int q    = lane & 3;
    float sum = 0.0f;
    if (blockIdx.x < POS_BLOCKS) {
        int wave = (blockIdx.x * blockDim.x + threadIdx.x) >> 6;
        int nwaves = (POS_BLOCKS * 256) >> 6;
        for (int base = wave * 16; base < E_TOTAL; base += nwaves * 16) {
            int e = base + g;
            int s = ei[e];
            int t = ei[E_TOTAL + e];
            const uint4* ps = (const uint4*)(x + s * C + q * 32);
            const uint4* pt = (const uint4*)(x + t * C + q * 32);
            uint4 s0 = ps[0], s1 = ps[1], s2 = ps[2], s3 = ps[3];
            uint4 t0 = pt[0], t1 = pt[1], t2 = pt[2], t3 = pt[3];
            float p = dot_u(s0.x, t0.x) + dot_u(s0.y, t0.y) + dot_u(s0.z, t0.z) + dot_u(s0.w, t0.w)
                    + dot_u(s1.x, t1.x) + dot_u(s1.y, t1.y) + dot_u(s1.z, t1.z) + dot_u(s1.w, t1.w)
                    + dot_u(s2.x, t2.x) + dot_u(s2.y, t2.y) + dot_u(s2.z, t2.z) + dot_u(s2.w, t2.w)
                    + dot_u(s3.x, t3.x) + dot_u(s3.y, t3.y) + dot_u(s3.z, t3.z) + dot_u(s3.w, t3.w);
            p += __shfl_xor(p, 1, 64);
            p += __shfl_xor(p, 2, 64);
            if (q == 0) sum += log_sigmoid(p * INV_TEMP);
        }
    } else {
        int bi = blockIdx.x - POS_BLOCKS;
        int wave = (bi * blockDim.x + threadIdx.x) >> 6;
        int nwaves = (NEG_BLOCKS * 256) >> 6;
        for (int base = wave * 16; base < N; base += nwaves * 16) {
            int i = base + g;
            int t = ridx[i];
            const uint4* ps = (const uint4*)(x + i * C + q * 32);
            const uint4* pt = (const uint4*)(x + t * C + q * 32);
            uint4 s0 = ps[0], s1 = ps[1], s2 = ps[2], s3 = ps[3];
            uint4 t0 = pt[0], t1 = pt[1], t2 = pt[2], t3 = pt[3];
            float p = dot_u(s0.x, t0.x) + dot_u(s0.y, t0.y) + dot_u(s0.z, t0.z) + dot_u(s0.w, t0.w)
                    + dot_u(s1.x, t1.x) + dot_u(s1.y, t1.y) + dot_u(s1.z, t1.z) + dot_u(s1.w, t1.w)
                    + dot_u(s2.x, t2.x) + dot_u(s2.y, t2.y) + dot_u(s2.z, t2.z) + dot_u(s2.w, t2.w)
                    + dot_u(s3.x, t3.x) + dot_u(s3.y, t3.y) + dot_u(s3.z, t3.z) + dot_u(s3.w, t3.w);
            p += __shfl_xor(p, 1, 64);
            p += __shfl_xor(p, 2, 64);
            if (q == 0) sum += log_sigmoid(-p * INV_TEMP);
        }
    }
    sum += __shfl_xor(sum, 4, 64);
    sum += __shfl_xor(sum, 8, 64);
    sum += __shfl_xor(sum, 16, 64);
    sum += __shfl_xor(sum, 32, 64);
    if (lane == 0) wsum[threadIdx.x >> 6] = sum;
    __syncthreads();
    if (threadIdx.x == 0) {
        float v = (wsum[0] + wsum[1]) + (wsum[2] + wsum[3]);
        if (blockIdx.x < POS_BLOCKS) ppos[blockIdx.x] = v;
        else                         pneg[blockIdx.x - POS_BLOCKS] = v;
    }
}

__global__ void finalize_kernel(const float* __restrict__ ppos,
                                const float* __restrict__ pneg,
                                float* __restrict__ out) {
    __shared__ float red[256];
    int t = threadIdx.x;
    float s = 0.0f;
    for (int i = t; i < POS_BLOCKS; i += 256) s += ppos[i];
    float sn = (t < NEG_BLOCKS) ? pneg[t] : 0.0f;
    red[t] = s * (-1.0f / (float)E_TOTAL) + sn * (-1.0f / (float)N);
    __syncthreads();
    for (int off = 128; off > 0; off >>= 1) {
        if (t < off) red[t] += red[t + off];
        __syncthreads();
    }
    if (t == 0) out[0] = red[0];
}

extern "C" void kernel_launch(void* const* d_in, const int* in_sizes, int n_in,
                              void* d_out, int out_size, void* d_ws, size_t ws_size,
                              hipStream_t stream) {
    (void)in_sizes; (void)n_in; (void)out_size; (void)ws_size;

    const float* emb_in = (const float*)d_in[0];
    const int*   ei     = (const int*)d_in[1];   // (2, E) flattened: src then dst
    const int*   ridx   = (const int*)d_in[2];
    float* out = (float*)d_out;

    char* ws = (char*)d_ws;
    uint*         bar   = (uint*)(ws + OFF_BAR);
    unsigned int* bm    = (unsigned int*)(ws + OFF_BITMAP);
    float*        dinvs = (float*)(ws + OFF_DINV);
    int*          cnt   = (int*)(ws + OFF_CNT);
    float*        part  = (float*)(ws + OFF_PART);
    float*        pneg  = (float*)(ws + OFF_PNEG);
    int*          ellc  = (int*)(ws + OFF_ELL);
    ushort*       bufA  = (ushort*)(ws + OFF_BUFA);
    ushort*       bufB  = (ushort*)(ws + OFF_BUFB);

    // one memset zeroes barrier state + dedup bitmap (contiguous, r4-proven)
    hipMemsetAsync(ws + OFF_BAR, 0, BAR_BYTES + BITMAP_BYTES, stream);

    void* args[] = { (void*)&emb_in, (void*)&ei, (void*)&ridx, (void*)&dinvs,
                     (void*)&part,   (void*)&bm, (void*)&bar,  (void*)&bufA,
                     (void*)&bufB,   (void*)&out };
    hipError_t rc = hipLaunchCooperativeKernel(
        reinterpret_cast<void*>(mega_kernel),
        dim3(BLOCKS), dim3(THREADS), args, 0, stream);

    if (rc != hipSuccess) {
        // Fallback: proven multi-kernel path (bitmap already zeroed above).
        ushort* buf[2] = {bufA, bufB};
        scatter_edges_kernel<<<E_TOTAL / 256, 256, 0, stream>>>(ei, bm, bufA, bufB);
        build_ell_kernel<<<N / 4, 256, 0, stream>>>(bm, cnt, ellc, dinvs);
        for (int s = 0; s < STEPS; ++s) {
            const void* xs = (s == 0) ? (const void*)emb_in : (const void*)buf[s & 1];
            ushort* yd = buf[(s + 1) & 1];
            spmm_step_kernel<<<N / 4, 256, 0, stream>>>(cnt, ellc, dinvs, xs, yd,
                                                        s == 0 ? 1 : 0,
                                                        s == STEPS - 1 ? 1 : 0);
        }
        const ushort* emb = buf[STEPS & 1];
        loss_kernel<<<POS_BLOCKS + NEG_BLOCKS, 256, 0, stream>>>(emb, ei, ridx, part, pneg);
        finalize_kernel<<<1, 256, 0, stream>>>(part, pneg, out);
    }
}